// Round 4
// baseline (560.898 us; speedup 1.0000x reference)
//
#include <hip/hip_runtime.h>
#include <math.h>

constexpr int cE = 8;
constexpr int cH = 1024;
constexpr int cF = 2816;
constexpr int cR = 256;
constexpr int cT = 2048;
constexpr int ROWS = cT * 2;   // total routed (token, expert) rows = T*K
constexpr int LDA = 40;        // padded LDS row stride (BK=32 kernels)
constexpr int LDK = 72;        // padded LDS row stride (BK=64 kernels)

using short8  = __attribute__((ext_vector_type(8))) short;
using float4v = __attribute__((ext_vector_type(4))) float;
#define MFMA16 __builtin_amdgcn_mfma_f32_16x16x32_bf16

__device__ __forceinline__ unsigned short f2bf(float f) {
  union { float f; unsigned u; } v; v.f = f;
  unsigned r = v.u + 0x7fffu + ((v.u >> 16) & 1u);   // RNE
  return (unsigned short)(r >> 16);
}
__device__ __forceinline__ float bf2f(unsigned short s) {
  union { unsigned u; float f; } v; v.u = (unsigned)s << 16; return v.f;
}

// pack 8 fp32 -> 8 bf16, single 16B store
__device__ __forceinline__ void store_bf8(unsigned short* dst, float4 a, float4 b) {
  union { unsigned short u[8]; uint4 v; } t;
  t.u[0] = f2bf(a.x); t.u[1] = f2bf(a.y); t.u[2] = f2bf(a.z); t.u[3] = f2bf(a.w);
  t.u[4] = f2bf(b.x); t.u[5] = f2bf(b.y); t.u[6] = f2bf(b.z); t.u[7] = f2bf(b.w);
  *reinterpret_cast<uint4*>(dst) = t.v;
}

// ---------------------------------------------------------------------------
// gating: logits = x @ gate_w, top-2, renormalized weights
// ---------------------------------------------------------------------------
__global__ __launch_bounds__(256) void k_gating(
    const float* __restrict__ x, const float* __restrict__ gw,
    int* __restrict__ et, float* __restrict__ wt)
{
  __shared__ float gws[cH * cE];
  const int tid = threadIdx.x;
  for (int i = tid; i < cH * cE; i += 256) gws[i] = gw[i];
  __syncthreads();
  const int t = blockIdx.x * 256 + tid;
  const float4* xr = reinterpret_cast<const float4*>(x + (long)t * cH);
  float l[cE];
#pragma unroll
  for (int e = 0; e < cE; ++e) l[e] = 0.f;
  for (int h4 = 0; h4 < cH / 4; ++h4) {
    float4 v = xr[h4];
    const float* g0 = &gws[(h4 * 4 + 0) * cE];
    const float* g1 = &gws[(h4 * 4 + 1) * cE];
    const float* g2 = &gws[(h4 * 4 + 2) * cE];
    const float* g3 = &gws[(h4 * 4 + 3) * cE];
#pragma unroll
    for (int e = 0; e < cE; ++e)
      l[e] += v.x * g0[e] + v.y * g1[e] + v.z * g2[e] + v.w * g3[e];
  }
  int i0 = 0; float m0 = l[0];
#pragma unroll
  for (int e = 1; e < cE; ++e) if (l[e] > m0) { m0 = l[e]; i0 = e; }
  int i1 = -1; float m1 = -1e30f;
#pragma unroll
  for (int e = 0; e < cE; ++e) if (e != i0 && l[e] > m1) { m1 = l[e]; i1 = e; }
  float w0 = 1.f / (1.f + expf(m1 - m0));
  et[t * 2 + 0] = i0;  et[t * 2 + 1] = i1;
  wt[t * 2 + 0] = w0;  wt[t * 2 + 1] = 1.f - w0;
}

// ---------------------------------------------------------------------------
// build compact per-expert token lists + inverse map (single block)
// ---------------------------------------------------------------------------
__global__ __launch_bounds__(256) void k_lists(
    const int* __restrict__ et, int* __restrict__ rowmap,
    int* __restrict__ cnt, int* __restrict__ off)
{
  __shared__ int c[cE], p[cE], o[cE];
  const int tid = threadIdx.x;
  if (tid < cE) { c[tid] = 0; p[tid] = 0; }
  __syncthreads();
  for (int i = tid; i < ROWS; i += 256) atomicAdd(&c[et[i]], 1);
  __syncthreads();
  if (tid == 0) {
    int s = 0;
    for (int e = 0; e < cE; ++e) { o[e] = s; s += c[e]; }
  }
  __syncthreads();
  for (int i = tid; i < ROWS; i += 256) {
    int e = et[i];
    int slot = atomicAdd(&p[e], 1);
    rowmap[i] = o[e] + slot;
  }
  if (tid < cE) { cnt[tid] = c[tid]; off[tid] = o[tid]; }
}

// ---------------------------------------------------------------------------
// transpose + fp32->bf16: in [P][Q] per batch -> out [Q][P] per batch
// grid = (Q/32, P/32, batch)
// ---------------------------------------------------------------------------
__global__ __launch_bounds__(256) void k_tconv(
    const float* __restrict__ in, unsigned short* __restrict__ out, int P, int Q)
{
  __shared__ float tile[32][33];
  const long es = (long)P * Q;
  const int e = blockIdx.z;
  in += e * es; out += e * es;
  const int c0 = blockIdx.x * 32, r0 = blockIdx.y * 32;
  const int tid = threadIdx.x;
  const int r = tid >> 3, c4 = (tid & 7) * 4;
  float4 v = *reinterpret_cast<const float4*>(in + (long)(r0 + r) * Q + c0 + c4);
  tile[r][c4 + 0] = v.x; tile[r][c4 + 1] = v.y;
  tile[r][c4 + 2] = v.z; tile[r][c4 + 3] = v.w;
  __syncthreads();
  const int cc = tid >> 3, rr4 = (tid & 7) * 4;
  ushort4 o;
  o.x = f2bf(tile[rr4 + 0][cc]);
  o.y = f2bf(tile[rr4 + 1][cc]);
  o.z = f2bf(tile[rr4 + 2][cc]);
  o.w = f2bf(tile[rr4 + 3][cc]);
  *reinterpret_cast<ushort4*>(out + (long)(c0 + cc) * P + r0 + rr4) = o;
}

// ---------------------------------------------------------------------------
// MFMA fold: D[m][n] = sum_k A[m][k] * B[n][k],  K = 256 fixed.
// A bf16 [M][256] (stride sA per expert; 0 = shared), B fp32 [N][256]
// (stride sB; 0 = shared), D bf16 [M][ldd] row-major (stride sD).
// tile 128x64, BK=32, register prefetch. grid = (N/64, M/128, E)
// ---------------------------------------------------------------------------
__global__ __launch_bounds__(256, 3) void k_foldm(
    const unsigned short* __restrict__ A, long sA,
    const float* __restrict__ B, long sB,
    unsigned short* __restrict__ D, long sD, int ldd)
{
  __shared__ __align__(16) unsigned short As[128 * LDA], Bs[64 * LDA];
  const int e = blockIdx.z;
  A += e * sA; B += e * sB; D += e * sD;
  const int m0 = blockIdx.y * 128, n0 = blockIdx.x * 64;
  const int tid = threadIdx.x;
  const int sr = tid >> 2, sk = (tid & 3) * 8;
  const unsigned short* a0 = A + (long)(m0 + sr) * 256 + sk;
  const unsigned short* a1 = a0 + (long)64 * 256;
  const float* br = B + (long)(n0 + sr) * 256 + sk;
  uint4 rA0, rA1; float4 rB0, rB1;
  auto load_slice = [&](int k0) {
    rA0 = *reinterpret_cast<const uint4*>(a0 + k0);
    rA1 = *reinterpret_cast<const uint4*>(a1 + k0);
    rB0 = *reinterpret_cast<const float4*>(br + k0);
    rB1 = *reinterpret_cast<const float4*>(br + k0 + 4);
  };
  load_slice(0);
  const int wid = tid >> 6, lane = tid & 63;
  const int wm = (wid >> 1) * 64, wn = (wid & 1) * 32;
  const int fr = lane & 15, fq = lane >> 4;
  float4v zf = {0.f, 0.f, 0.f, 0.f};
  float4v acc[4][2];
#pragma unroll
  for (int i = 0; i < 4; ++i) { acc[i][0] = zf; acc[i][1] = zf; }
  for (int k0 = 0; k0 < 256; k0 += 32) {
    *reinterpret_cast<uint4*>(&As[sr * LDA + sk]) = rA0;
    *reinterpret_cast<uint4*>(&As[(sr + 64) * LDA + sk]) = rA1;
    store_bf8(&Bs[sr * LDA + sk], rB0, rB1);
    if (k0 + 32 < 256) load_slice(k0 + 32);
    __syncthreads();
    short8 af[4], bf[2];
#pragma unroll
    for (int mi = 0; mi < 4; ++mi)
      af[mi] = *reinterpret_cast<const short8*>(&As[(wm + mi * 16 + fr) * LDA + fq * 8]);
#pragma unroll
    for (int nj = 0; nj < 2; ++nj)
      bf[nj] = *reinterpret_cast<const short8*>(&Bs[(wn + nj * 16 + fr) * LDA + fq * 8]);
#pragma unroll
    for (int mi = 0; mi < 4; ++mi)
#pragma unroll
      for (int nj = 0; nj < 2; ++nj)
        acc[mi][nj] = MFMA16(af[mi], bf[nj], acc[mi][nj], 0, 0, 0);
    __syncthreads();
  }
#pragma unroll
  for (int mi = 0; mi < 4; ++mi)
#pragma unroll
    for (int r = 0; r < 4; ++r) {
      int m = m0 + wm + mi * 16 + fq * 4 + r;
#pragma unroll
      for (int nj = 0; nj < 2; ++nj)
        D[(long)m * ldd + n0 + wn + nj * 16 + fr] = f2bf(acc[mi][nj][r]);
    }
}

// ---------------------------------------------------------------------------
// DENSE t1 GEMM + scatter epilogue.
// C[2048][4096] = x @ b1t^T; each 128x128 tile writes only rows routed to
// this tile's expert, into compact t1[row][512]. Tile 128x128, BK=64,
// register prefetch. grid = (32, 16)
// ---------------------------------------------------------------------------
__global__ __launch_bounds__(256, 2) void k_t1d(
    const float* __restrict__ x, const unsigned short* __restrict__ b1t,
    unsigned short* __restrict__ t1, const int* __restrict__ et,
    const int* __restrict__ rowmap)
{
  __shared__ __align__(16) unsigned short As[128 * LDK];
  __shared__ __align__(16) unsigned short Bs[128 * LDK];
  const int tid = threadIdx.x;
  const int m0 = blockIdx.y * 128;
  const int nb = blockIdx.x;                 // 0..31
  const int sr = tid >> 2, sk16 = (tid & 3) * 16;
  const float* A0 = x + (long)(m0 + sr) * cH + sk16;
  const float* A1 = A0 + (long)64 * cH;
  const unsigned short* B0 = b1t + (long)(nb * 128 + sr) * cH + sk16;
  const unsigned short* B1 = B0 + (long)64 * cH;
  float4 ra0[4], ra1[4];
  uint4  rb0[2], rb1[2];
  auto load_slice = [&](int k0) {
#pragma unroll
    for (int i = 0; i < 4; ++i) {
      ra0[i] = *reinterpret_cast<const float4*>(A0 + k0 + i * 4);
      ra1[i] = *reinterpret_cast<const float4*>(A1 + k0 + i * 4);
    }
#pragma unroll
    for (int i = 0; i < 2; ++i) {
      rb0[i] = *reinterpret_cast<const uint4*>(B0 + k0 + i * 8);
      rb1[i] = *reinterpret_cast<const uint4*>(B1 + k0 + i * 8);
    }
  };
  load_slice(0);
  const int wid = tid >> 6, lane = tid & 63;
  const int wm = (wid >> 1) * 64, wn = (wid & 1) * 64;
  const int fr = lane & 15, fq = lane >> 4;
  float4v zf = {0.f, 0.f, 0.f, 0.f};
  float4v acc[4][4];
#pragma unroll
  for (int i = 0; i < 4; ++i)
#pragma unroll
    for (int j = 0; j < 4; ++j) acc[i][j] = zf;
  for (int k0 = 0; k0 < cH; k0 += 64) {
    store_bf8(&As[sr * LDK + sk16], ra0[0], ra0[1]);
    store_bf8(&As[sr * LDK + sk16 + 8], ra0[2], ra0[3]);
    store_bf8(&As[(sr + 64) * LDK + sk16], ra1[0], ra1[1]);
    store_bf8(&As[(sr + 64) * LDK + sk16 + 8], ra1[2], ra1[3]);
    *reinterpret_cast<uint4*>(&Bs[sr * LDK + sk16]) = rb0[0];
    *reinterpret_cast<uint4*>(&Bs[sr * LDK + sk16 + 8]) = rb0[1];
    *reinterpret_cast<uint4*>(&Bs[(sr + 64) * LDK + sk16]) = rb1[0];
    *reinterpret_cast<uint4*>(&Bs[(sr + 64) * LDK + sk16 + 8]) = rb1[1];
    if (k0 + 64 < cH) load_slice(k0 + 64);
    __syncthreads();
#pragma unroll
    for (int ks = 0; ks < 2; ++ks) {
      short8 af[4], bf[4];
#pragma unroll
      for (int mi = 0; mi < 4; ++mi)
        af[mi] = *reinterpret_cast<const short8*>(
            &As[(wm + mi * 16 + fr) * LDK + ks * 32 + fq * 8]);
#pragma unroll
      for (int nj = 0; nj < 4; ++nj)
        bf[nj] = *reinterpret_cast<const short8*>(
            &Bs[(wn + nj * 16 + fr) * LDK + ks * 32 + fq * 8]);
#pragma unroll
      for (int mi = 0; mi < 4; ++mi)
#pragma unroll
        for (int nj = 0; nj < 4; ++nj)
          acc[mi][nj] = MFMA16(af[mi], bf[nj], acc[mi][nj], 0, 0, 0);
    }
    __syncthreads();
  }
  const int e_t = nb >> 2;
  const int colbase = (nb & 3) * 128 + wn;
#pragma unroll
  for (int mi = 0; mi < 4; ++mi)
#pragma unroll
    for (int r = 0; r < 4; ++r) {
      int t = m0 + wm + mi * 16 + fq * 4 + r;
      int crow = -1;
      if (et[2 * t] == e_t) crow = rowmap[2 * t];
      else if (et[2 * t + 1] == e_t) crow = rowmap[2 * t + 1];
      if (crow >= 0) {
#pragma unroll
        for (int nj = 0; nj < 4; ++nj)
          t1[(long)crow * 512 + colbase + nj * 16 + fr] = f2bf(acc[mi][nj][r]);
      }
    }
}

// ---------------------------------------------------------------------------
// dual GEMM: a = silu(t1g @ vgT^T) * (t1u @ vuT^T)  [rows x F], K=256
// tile 128x64, BK=32, register prefetch.  grid = (44, 16, E)
// ---------------------------------------------------------------------------
__global__ __launch_bounds__(256, 3) void k_act(
    const unsigned short* __restrict__ t1,
    const unsigned short* __restrict__ vgT, const unsigned short* __restrict__ vuT,
    unsigned short* __restrict__ a, const int* __restrict__ cnt,
    const int* __restrict__ off)
{
  __shared__ __align__(16) unsigned short Ag[128 * LDA], Au[128 * LDA];
  __shared__ __align__(16) unsigned short Bg[64 * LDA],  Bu[64 * LDA];
  const int e = blockIdx.z, c = cnt[e], o = off[e];
  const int m0 = blockIdx.y * 128;
  if (m0 >= c) return;
  const int n0 = blockIdx.x * 64;
  const int tid = threadIdx.x;
  const int sr = tid >> 2, sk = (tid & 3) * 8;
  const unsigned short* ar0 = (m0 + sr < c)      ? t1 + (long)(o + m0 + sr) * 512 + sk      : nullptr;
  const unsigned short* ar1 = (m0 + 64 + sr < c) ? t1 + (long)(o + m0 + 64 + sr) * 512 + sk : nullptr;
  const unsigned short* Btg = vgT + (long)e * cF * 256 + (long)(n0 + sr) * 256 + sk;
  const unsigned short* Btu = vuT + (long)e * cF * 256 + (long)(n0 + sr) * 256 + sk;
  const uint4 zu = make_uint4(0u, 0u, 0u, 0u);
  uint4 rg0, ru0, rg1, ru1, rbg, rbu;
  auto load_slice = [&](int k0) {
    rg0 = ar0 ? *reinterpret_cast<const uint4*>(ar0 + k0)       : zu;
    ru0 = ar0 ? *reinterpret_cast<const uint4*>(ar0 + 256 + k0) : zu;
    rg1 = ar1 ? *reinterpret_cast<const uint4*>(ar1 + k0)       : zu;
    ru1 = ar1 ? *reinterpret_cast<const uint4*>(ar1 + 256 + k0) : zu;
    rbg = *reinterpret_cast<const uint4*>(Btg + k0);
    rbu = *reinterpret_cast<const uint4*>(Btu + k0);
  };
  load_slice(0);
  const int wid = tid >> 6, lane = tid & 63;
  const int wm = (wid >> 1) * 64, wn = (wid & 1) * 32;
  const int fr = lane & 15, fq = lane >> 4;
  float4v zf = {0.f, 0.f, 0.f, 0.f};
  float4v accg[4][2], accu[4][2];
#pragma unroll
  for (int i = 0; i < 4; ++i) { accg[i][0] = zf; accg[i][1] = zf; accu[i][0] = zf; accu[i][1] = zf; }
  for (int k0 = 0; k0 < 256; k0 += 32) {
    *reinterpret_cast<uint4*>(&Ag[sr * LDA + sk]) = rg0;
    *reinterpret_cast<uint4*>(&Au[sr * LDA + sk]) = ru0;
    *reinterpret_cast<uint4*>(&Ag[(sr + 64) * LDA + sk]) = rg1;
    *reinterpret_cast<uint4*>(&Au[(sr + 64) * LDA + sk]) = ru1;
    *reinterpret_cast<uint4*>(&Bg[sr * LDA + sk]) = rbg;
    *reinterpret_cast<uint4*>(&Bu[sr * LDA + sk]) = rbu;
    if (k0 + 32 < 256) load_slice(k0 + 32);
    __syncthreads();
    short8 ag[4], au[4], bg[2], bu[2];
#pragma unroll
    for (int mi = 0; mi < 4; ++mi) {
      ag[mi] = *reinterpret_cast<const short8*>(&Ag[(wm + mi * 16 + fr) * LDA + fq * 8]);
      au[mi] = *reinterpret_cast<const short8*>(&Au[(wm + mi * 16 + fr) * LDA + fq * 8]);
    }
#pragma unroll
    for (int nj = 0; nj < 2; ++nj) {
      bg[nj] = *reinterpret_cast<const short8*>(&Bg[(wn + nj * 16 + fr) * LDA + fq * 8]);
      bu[nj] = *reinterpret_cast<const short8*>(&Bu[(wn + nj * 16 + fr) * LDA + fq * 8]);
    }
#pragma unroll
    for (int mi = 0; mi < 4; ++mi)
#pragma unroll
      for (int nj = 0; nj < 2; ++nj) {
        accg[mi][nj] = MFMA16(ag[mi], bg[nj], accg[mi][nj], 0, 0, 0);
        accu[mi][nj] = MFMA16(au[mi], bu[nj], accu[mi][nj], 0, 0, 0);
      }
    __syncthreads();
  }
#pragma unroll
  for (int mi = 0; mi < 4; ++mi)
#pragma unroll
    for (int r = 0; r < 4; ++r) {
      int row = m0 + wm + mi * 16 + fq * 4 + r;
      if (row < c) {
#pragma unroll
        for (int nj = 0; nj < 2; ++nj) {
          float g = accg[mi][nj][r];
          float u = accu[mi][nj][r];
          float s = g / (1.f + expf(-g)) * u;
          a[(long)(o + row) * cF + n0 + wn + nj * 16 + fr] = f2bf(s);
        }
      }
    }
}

// ---------------------------------------------------------------------------
// t3p[ks] = a @ udT^T (split-K=2, PLAIN fp32 stores — no atomics)
// [2][ROWS][256], K-half = 1408. tile 64x64, BK=64, register prefetch.
// grid = (8, 32, E): blockIdx.x = n_tile(0..3) | ksplit(0..1)<<2
// ---------------------------------------------------------------------------
__global__ __launch_bounds__(256, 4) void k_t3(
    const unsigned short* __restrict__ a, const unsigned short* __restrict__ udT,
    float* __restrict__ t3p, const int* __restrict__ cnt,
    const int* __restrict__ off)
{
  __shared__ __align__(16) unsigned short As[64 * LDK], Bs[64 * LDK];
  const int e = blockIdx.z, c = cnt[e], o = off[e];
  const int m0 = blockIdx.y * 64;
  if (m0 >= c) return;
  const int n0 = (blockIdx.x & 3) * 64;
  const int ksp = blockIdx.x >> 2;                 // 0..1
  const int kbase = ksp * 1408;
  const int tid = threadIdx.x;
  const int sr = tid >> 2, sk16 = (tid & 3) * 16;
  const unsigned short* arow = (m0 + sr < c)
      ? a + (long)(o + m0 + sr) * cF + sk16 : nullptr;
  const unsigned short* brow = udT + (long)e * 256 * cF + (long)(n0 + sr) * cF + sk16;
  const uint4 zu = make_uint4(0u, 0u, 0u, 0u);
  uint4 rA[2], rB[2];
  auto load_slice = [&](int k0) {
    rA[0] = arow ? *reinterpret_cast<const uint4*>(arow + k0)     : zu;
    rA[1] = arow ? *reinterpret_cast<const uint4*>(arow + k0 + 8) : zu;
    rB[0] = *reinterpret_cast<const uint4*>(brow + k0);
    rB[1] = *reinterpret_cast<const uint4*>(brow + k0 + 8);
  };
  load_slice(kbase);
  const int wid = tid >> 6, lane = tid & 63;
  const int wm = (wid >> 1) * 32, wn = (wid & 1) * 32;
  const int fr = lane & 15, fq = lane >> 4;
  float4v zf = {0.f, 0.f, 0.f, 0.f};
  float4v acc[2][2] = {{zf, zf}, {zf, zf}};
  const int kend = kbase + 1408;
  for (int k0 = kbase; k0 < kend; k0 += 64) {
    *reinterpret_cast<uint4*>(&As[sr * LDK + sk16]) = rA[0];
    *reinterpret_cast<uint4*>(&As[sr * LDK + sk16 + 8]) = rA[1];
    *reinterpret_cast<uint4*>(&Bs[sr * LDK + sk16]) = rB[0];
    *reinterpret_cast<uint4*>(&Bs[sr * LDK + sk16 + 8]) = rB[1];
    if (k0 + 64 < kend) load_slice(k0 + 64);
    __syncthreads();
#pragma unroll
    for (int ks = 0; ks < 2; ++ks) {
      short8 af[2], bf[2];
#pragma unroll
      for (int mi = 0; mi < 2; ++mi)
        af[mi] = *reinterpret_cast<const short8*>(
            &As[(wm + mi * 16 + fr) * LDK + ks * 32 + fq * 8]);
#pragma unroll
      for (int nj = 0; nj < 2; ++nj)
        bf[nj] = *reinterpret_cast<const short8*>(
            &Bs[(wn + nj * 16 + fr) * LDK + ks * 32 + fq * 8]);
#pragma unroll
      for (int mi = 0; mi < 2; ++mi)
#pragma unroll
        for (int nj = 0; nj < 2; ++nj)
          acc[mi][nj] = MFMA16(af[mi], bf[nj], acc[mi][nj], 0, 0, 0);
    }
    __syncthreads();
  }
  float* dstbase = t3p + (long)ksp * ROWS * 256;
#pragma unroll
  for (int mi = 0; mi < 2; ++mi)
#pragma unroll
    for (int r = 0; r < 4; ++r) {
      int row = m0 + wm + mi * 16 + fq * 4 + r;
      if (row < c) {
        float* dst = dstbase + (long)(o + row) * 256 + n0 + wn;
#pragma unroll
        for (int nj = 0; nj < 2; ++nj)
          dst[nj * 16 + fr] = acc[mi][nj][r];
      }
    }
}

// ---------------------------------------------------------------------------
// y = (t3p0 + t3p1) @ vd2t^T   [rows x 1024] bf16, PLAIN stores. K = 256.
// Partials summed in-register during staging. tile 128x64, BK=32.
// grid = (16, 16, E)
// ---------------------------------------------------------------------------
__global__ __launch_bounds__(256, 3) void k_y(
    const float* __restrict__ t3p, const unsigned short* __restrict__ vd2t,
    unsigned short* __restrict__ y, const int* __restrict__ cnt,
    const int* __restrict__ off)
{
  __shared__ __align__(16) unsigned short As[128 * LDA], Bs[64 * LDA];
  const int e = blockIdx.z, c = cnt[e], o = off[e];
  const int m0 = blockIdx.y * 128;
  if (m0 >= c) return;
  const int n0 = blockIdx.x * 64;
  const int tid = threadIdx.x;
  const int sr = tid >> 2, sk = (tid & 3) * 8;
  const long psz = (long)ROWS * 256;
  const float* ar0 = (m0 + sr < c)      ? t3p + (long)(o + m0 + sr) * 256 + sk      : nullptr;
  const float* ar1 = (m0 + 64 + sr < c) ? t3p + (long)(o + m0 + 64 + sr) * 256 + sk : nullptr;
  const unsigned short* brow = vd2t + (long)e * cH * 256 + (long)(n0 + sr) * 256 + sk;
  const float4 z4 = make_float4(0.f, 0.f, 0.f, 0.f);
  float4 rA0[2], rA1[2];
  uint4 rB;
  auto add4 = [](float4 a, float4 b) {
    return make_float4(a.x + b.x, a.y + b.y, a.z + b.z, a.w + b.w);
  };
  auto load_slice = [&](int k0) {
    rA0[0] = ar0 ? add4(*reinterpret_cast<const float4*>(ar0 + k0),
                        *reinterpret_cast<const float4*>(ar0 + psz + k0)) : z4;
    rA0[1] = ar0 ? add4(*reinterpret_cast<const float4*>(ar0 + k0 + 4),
                        *reinterpret_cast<const float4*>(ar0 + psz + k0 + 4)) : z4;
    rA1[0] = ar1 ? add4(*reinterpret_cast<const float4*>(ar1 + k0),
                        *reinterpret_cast<const float4*>(ar1 + psz + k0)) : z4;
    rA1[1] = ar1 ? add4(*reinterpret_cast<const float4*>(ar1 + k0 + 4),
                        *reinterpret_cast<const float4*>(ar1 + psz + k0 + 4)) : z4;
    rB = *reinterpret_cast<const uint4*>(brow + k0);
  };
  load_slice(0);
  const int wid = tid >> 6, lane = tid & 63;
  const int wm = (wid >> 1) * 64, wn = (wid & 1) * 32;
  const int fr = lane & 15, fq = lane >> 4;
  float4v zf = {0.f, 0.f, 0.f, 0.f};
  float4v acc[4][2];
#pragma unroll
  for (int i = 0; i < 4; ++i) { acc[i][0] = zf; acc[i][1] = zf; }
  for (int k0 = 0; k0 < 256; k0 += 32) {
    store_bf8(&As[sr * LDA + sk], rA0[0], rA0[1]);
    store_bf8(&As[(sr + 64) * LDA + sk], rA1[0], rA1[1]);
    *reinterpret_cast<uint4*>(&Bs[sr * LDA + sk]) = rB;
    if (k0 + 32 < 256) load_slice(k0 + 32);
    __syncthreads();
    short8 af[4], bf[2];
#pragma unroll
    for (int mi = 0; mi < 4; ++mi)
      af[mi] = *reinterpret_cast<const short8*>(&As[(wm + mi * 16 + fr) * LDA + fq * 8]);
#pragma unroll
    for (int nj = 0; nj < 2; ++nj)
      bf[nj] = *reinterpret_cast<const short8*>(&Bs[(wn + nj * 16 + fr) * LDA + fq * 8]);
#pragma unroll
    for (int mi = 0; mi < 4; ++mi)
#pragma unroll
      for (int nj = 0; nj < 2; ++nj)
        acc[mi][nj] = MFMA16(af[mi], bf[nj], acc[mi][nj], 0, 0, 0);
    __syncthreads();
  }
#pragma unroll
  for (int mi = 0; mi < 4; ++mi)
#pragma unroll
    for (int r = 0; r < 4; ++r) {
      int row = m0 + wm + mi * 16 + fq * 4 + r;
      if (row < c) {
#pragma unroll
        for (int nj = 0; nj < 2; ++nj)
          y[(long)(o + row) * cH + n0 + wn + nj * 16 + fr] = f2bf(acc[mi][nj][r]);
      }
    }
}

// ---------------------------------------------------------------------------
// out[t] = w0 * y[rowmap[2t]] + w1 * y[rowmap[2t+1]]   (pure write, no zero)
// grid = (T/2), 256 threads; 8 elements/thread.
// ---------------------------------------------------------------------------
__global__ __launch_bounds__(256) void k_combine(
    const unsigned short* __restrict__ y, const float* __restrict__ wt,
    const int* __restrict__ rowmap, float* __restrict__ out)
{
  const int tid = threadIdx.x;
  const int t = blockIdx.x * 2 + (tid >> 7);
  const int h = (tid & 127) * 8;
  const int r0 = rowmap[2 * t], r1 = rowmap[2 * t + 1];
  const float w0 = wt[2 * t], w1 = wt[2 * t + 1];
  union { uint4 v; unsigned short s[8]; } ua, ub;
  ua.v = *reinterpret_cast<const uint4*>(y + (long)r0 * cH + h);
  ub.v = *reinterpret_cast<const uint4*>(y + (long)r1 * cH + h);
  float o[8];
#pragma unroll
  for (int i = 0; i < 8; ++i)
    o[i] = w0 * bf2f(ua.s[i]) + w1 * bf2f(ub.s[i]);
  float* dst = out + (long)t * cH + h;
  *reinterpret_cast<float4*>(dst)     = make_float4(o[0], o[1], o[2], o[3]);
  *reinterpret_cast<float4*>(dst + 4) = make_float4(o[4], o[5], o[6], o[7]);
}

// ---------------------------------------------------------------------------
extern "C" void kernel_launch(void* const* d_in, const int* in_sizes, int n_in,
                              void* d_out, int out_size, void* d_ws, size_t ws_size,
                              hipStream_t stream)
{
  const float* x  = (const float*)d_in[0];
  const float* gw = (const float*)d_in[1];
  const float* Ug = (const float*)d_in[2];
  const float* Cg = (const float*)d_in[3];
  const float* Vg = (const float*)d_in[4];
  const float* Uu = (const float*)d_in[5];
  const float* Cu = (const float*)d_in[6];
  const float* Vu = (const float*)d_in[7];
  const float* Ud = (const float*)d_in[8];
  const float* Cd = (const float*)d_in[9];
  const float* Vd = (const float*)d_in[10];
  float* out = (float*)d_out;

  // workspace layout (~79 MiB peak, with aliasing)
  char* w = (char*)d_ws;
  // region shared by b1t (phase 1) then t3p (phase 2) — both 8.39 MB
  unsigned short* b1t = (unsigned short*)w;
  float*          t3p = (float*)w;          w += (long)cE * 512 * 1024 * 2;
  unsigned short* vd2t = (unsigned short*)w; w += (long)cE * cH * 256 * 2;    // 4.19
  // region shared by vgT (phase 1) then y (phase 2): 11.53 >= 8.39
  unsigned short* vgT = (unsigned short*)w;
  unsigned short* yb  = (unsigned short*)w;  w += (long)cE * cF * 256 * 2;    // 11.53
  unsigned short* vuT = (unsigned short*)w;  w += (long)cE * cF * 256 * 2;    // 11.53
  unsigned short* udT = (unsigned short*)w;  w += (long)cE * 256 * cF * 2;    // 11.53
  unsigned short* VdT = (unsigned short*)w;  w += (long)cE * cH * 256 * 2;    // 4.19
  unsigned short* CgT = (unsigned short*)w;  w += (long)cR * cR * 2;          // 0.13
  unsigned short* CuT = (unsigned short*)w;  w += (long)cR * cR * 2;          // 0.13
  unsigned short* t1  = (unsigned short*)w;  w += (long)ROWS * 512 * 2;       // 4.19
  unsigned short* ab  = (unsigned short*)w;  w += (long)ROWS * cF * 2;        // 23.07
  float* wt   = (float*)w; w += ROWS * 4;
  int* et     = (int*)w; w += ROWS * 4;
  int* rowmap = (int*)w; w += ROWS * 4;
  int* cnt = (int*)w; w += cE * 4;
  int* off = (int*)w; w += cE * 4;

  // 1. gating + lists
  k_gating<<<dim3(cT / 256), dim3(256), 0, stream>>>(x, gw, et, wt);
  k_lists<<<dim3(1), dim3(256), 0, stream>>>(et, rowmap, cnt, off);
  // 2. transposes (fp32 -> bf16)
  k_tconv<<<dim3(cR / 32, cR / 32, 1), dim3(256), 0, stream>>>(Cg, CgT, cR, cR);
  k_tconv<<<dim3(cR / 32, cR / 32, 1), dim3(256), 0, stream>>>(Cu, CuT, cR, cR);
  k_tconv<<<dim3(cH / 32, cR / 32, cE), dim3(256), 0, stream>>>(Vd, VdT, cR, cH);
  k_tconv<<<dim3(cF / 32, cR / 32, cE), dim3(256), 0, stream>>>(Vg, vgT, cR, cF);
  k_tconv<<<dim3(cF / 32, cR / 32, cE), dim3(256), 0, stream>>>(Vu, vuT, cR, cF);
  k_tconv<<<dim3(cR / 32, cF / 32, cE), dim3(256), 0, stream>>>(Ud, udT, cF, cR);
  // 3. MFMA folds (all K=256)
  //    b1t[e][r][h]     = sum_k CgT[r][k] * Ug[e][h][k]   (M=256, N=1024)
  k_foldm<<<dim3(cH / 64, cR / 128, cE), dim3(256), 0, stream>>>(
      CgT, 0, Ug, (long)cH * cR, b1t, (long)512 * 1024, cH);
  //    b1t[e][256+r][h] = sum_k CuT[r][k] * Uu[e][h][k]
  k_foldm<<<dim3(cH / 64, cR / 128, cE), dim3(256), 0, stream>>>(
      CuT, 0, Uu, (long)cH * cR, b1t + (long)256 * 1024, (long)512 * 1024, cH);
  //    vd2t[e][h][r]    = sum_k VdT[e][h][k] * Cd[r][k]   (M=1024, N=256)
  k_foldm<<<dim3(cR / 64, cH / 128, cE), dim3(256), 0, stream>>>(
      VdT, (long)cH * cR, Cd, 0, vd2t, (long)cH * 256, cR);
  // 4. dense t1 GEMM + scatter into compact rows
  k_t1d<<<dim3(32, cT / 128), dim3(256), 0, stream>>>(x, b1t, t1, et, rowmap);
  // 5. a = silu(t1g @ Vg) * (t1u @ Vu)
  k_act<<<dim3(cF / 64, cT / 128, cE), dim3(256), 0, stream>>>(t1, vgT, vuT, ab, cnt, off);
  // 6. t3p = a @ Ud (split-K=2, plain stores; aliases dead b1t)
  k_t3<<<dim3(8, cT / 64, cE), dim3(256), 0, stream>>>(ab, udT, t3p, cnt, off);
  // 7. y = (t3p0+t3p1) @ Vd2 (plain bf16 stores; aliases dead vgT)
  k_y<<<dim3(cH / 64, cT / 128, cE), dim3(256), 0, stream>>>(t3p, vd2t, yb, cnt, off);
  // 8. out = w0*y[r0] + w1*y[r1]
  k_combine<<<dim3(cT / 2), dim3(256), 0, stream>>>(yb, wt, rowmap, out);
}

// Round 5
// 422.071 us; speedup vs baseline: 1.3289x; 1.3289x over previous
//
#include <hip/hip_runtime.h>
#include <math.h>

constexpr int cE = 8;
constexpr int cH = 1024;
constexpr int cF = 2816;
constexpr int cR = 256;
constexpr int cT = 2048;
constexpr int ROWS = cT * 2;   // total routed (token, expert) rows = T*K
constexpr int LDA = 40;        // padded LDS row stride (BK=32 kernels)
constexpr int LDK = 72;        // padded LDS row stride (BK=64 kernels)

using short8  = __attribute__((ext_vector_type(8))) short;
using float4v = __attribute__((ext_vector_type(4))) float;
#define MFMA16 __builtin_amdgcn_mfma_f32_16x16x32_bf16

__device__ __forceinline__ unsigned short f2bf(float f) {
  union { float f; unsigned u; } v; v.f = f;
  unsigned r = v.u + 0x7fffu + ((v.u >> 16) & 1u);   // RNE
  return (unsigned short)(r >> 16);
}
__device__ __forceinline__ float bf2f(unsigned short s) {
  union { unsigned u; float f; } v; v.u = (unsigned)s << 16; return v.f;
}

// pack 8 fp32 -> 8 bf16, single 16B store
__device__ __forceinline__ void store_bf8(unsigned short* dst, float4 a, float4 b) {
  union { unsigned short u[8]; uint4 v; } t;
  t.u[0] = f2bf(a.x); t.u[1] = f2bf(a.y); t.u[2] = f2bf(a.z); t.u[3] = f2bf(a.w);
  t.u[4] = f2bf(b.x); t.u[5] = f2bf(b.y); t.u[6] = f2bf(b.z); t.u[7] = f2bf(b.w);
  *reinterpret_cast<uint4*>(dst) = t.v;
}

// ---------------------------------------------------------------------------
// gating: logits = x @ gate_w, top-2, renormalized weights
// ---------------------------------------------------------------------------
__global__ __launch_bounds__(256) void k_gating(
    const float* __restrict__ x, const float* __restrict__ gw,
    int* __restrict__ et, float* __restrict__ wt)
{
  __shared__ float gws[cH * cE];
  const int tid = threadIdx.x;
  for (int i = tid; i < cH * cE; i += 256) gws[i] = gw[i];
  __syncthreads();
  const int t = blockIdx.x * 256 + tid;
  const float4* xr = reinterpret_cast<const float4*>(x + (long)t * cH);
  float l[cE];
#pragma unroll
  for (int e = 0; e < cE; ++e) l[e] = 0.f;
  for (int h4 = 0; h4 < cH / 4; ++h4) {
    float4 v = xr[h4];
    const float* g0 = &gws[(h4 * 4 + 0) * cE];
    const float* g1 = &gws[(h4 * 4 + 1) * cE];
    const float* g2 = &gws[(h4 * 4 + 2) * cE];
    const float* g3 = &gws[(h4 * 4 + 3) * cE];
#pragma unroll
    for (int e = 0; e < cE; ++e)
      l[e] += v.x * g0[e] + v.y * g1[e] + v.z * g2[e] + v.w * g3[e];
  }
  int i0 = 0; float m0 = l[0];
#pragma unroll
  for (int e = 1; e < cE; ++e) if (l[e] > m0) { m0 = l[e]; i0 = e; }
  int i1 = -1; float m1 = -1e30f;
#pragma unroll
  for (int e = 0; e < cE; ++e) if (e != i0 && l[e] > m1) { m1 = l[e]; i1 = e; }
  float w0 = 1.f / (1.f + expf(m1 - m0));
  et[t * 2 + 0] = i0;  et[t * 2 + 1] = i1;
  wt[t * 2 + 0] = w0;  wt[t * 2 + 1] = 1.f - w0;
}

// ---------------------------------------------------------------------------
// build compact per-expert token lists + inverse map (single block)
// ---------------------------------------------------------------------------
__global__ __launch_bounds__(256) void k_lists(
    const int* __restrict__ et, int* __restrict__ rowmap,
    int* __restrict__ cnt, int* __restrict__ off)
{
  __shared__ int c[cE], p[cE], o[cE];
  const int tid = threadIdx.x;
  if (tid < cE) { c[tid] = 0; p[tid] = 0; }
  __syncthreads();
  for (int i = tid; i < ROWS; i += 256) atomicAdd(&c[et[i]], 1);
  __syncthreads();
  if (tid == 0) {
    int s = 0;
    for (int e = 0; e < cE; ++e) { o[e] = s; s += c[e]; }
  }
  __syncthreads();
  for (int i = tid; i < ROWS; i += 256) {
    int e = et[i];
    int slot = atomicAdd(&p[e], 1);
    rowmap[i] = o[e] + slot;
  }
  if (tid < cE) { cnt[tid] = c[tid]; off[tid] = o[tid]; }
}

// ---------------------------------------------------------------------------
// transpose + fp32->bf16: in [P][Q] per batch -> out [Q][P] per batch
// grid = (Q/32, P/32, batch)
// ---------------------------------------------------------------------------
__global__ __launch_bounds__(256) void k_tconv(
    const float* __restrict__ in, unsigned short* __restrict__ out, int P, int Q)
{
  __shared__ float tile[32][33];
  const long es = (long)P * Q;
  const int e = blockIdx.z;
  in += e * es; out += e * es;
  const int c0 = blockIdx.x * 32, r0 = blockIdx.y * 32;
  const int tid = threadIdx.x;
  const int r = tid >> 3, c4 = (tid & 7) * 4;
  float4 v = *reinterpret_cast<const float4*>(in + (long)(r0 + r) * Q + c0 + c4);
  tile[r][c4 + 0] = v.x; tile[r][c4 + 1] = v.y;
  tile[r][c4 + 2] = v.z; tile[r][c4 + 3] = v.w;
  __syncthreads();
  const int cc = tid >> 3, rr4 = (tid & 7) * 4;
  ushort4 o;
  o.x = f2bf(tile[rr4 + 0][cc]);
  o.y = f2bf(tile[rr4 + 1][cc]);
  o.z = f2bf(tile[rr4 + 2][cc]);
  o.w = f2bf(tile[rr4 + 3][cc]);
  *reinterpret_cast<ushort4*>(out + (long)(c0 + cc) * P + r0 + rr4) = o;
}

// ---------------------------------------------------------------------------
// MFMA fold: D[m][n] = sum_k A[m][k] * B[n][k],  K = 256 fixed.
// tile 128x64, BK=32, register prefetch. grid = (N/64, M/128, E)
// launch_bounds(256,2): DO NOT cap VGPRs harder — a (256,4)-style cap makes
// the compiler delete the prefetch (r4 k_t3 lesson).
// ---------------------------------------------------------------------------
__global__ __launch_bounds__(256, 2) void k_foldm(
    const unsigned short* __restrict__ A, long sA,
    const float* __restrict__ B, long sB,
    unsigned short* __restrict__ D, long sD, int ldd)
{
  __shared__ __align__(16) unsigned short As[128 * LDA], Bs[64 * LDA];
  const int e = blockIdx.z;
  A += e * sA; B += e * sB; D += e * sD;
  const int m0 = blockIdx.y * 128, n0 = blockIdx.x * 64;
  const int tid = threadIdx.x;
  const int sr = tid >> 2, sk = (tid & 3) * 8;
  const unsigned short* a0 = A + (long)(m0 + sr) * 256 + sk;
  const unsigned short* a1 = a0 + (long)64 * 256;
  const float* br = B + (long)(n0 + sr) * 256 + sk;
  uint4 rA0, rA1; float4 rB0, rB1;
  auto load_slice = [&](int k0) {
    rA0 = *reinterpret_cast<const uint4*>(a0 + k0);
    rA1 = *reinterpret_cast<const uint4*>(a1 + k0);
    rB0 = *reinterpret_cast<const float4*>(br + k0);
    rB1 = *reinterpret_cast<const float4*>(br + k0 + 4);
  };
  load_slice(0);
  const int wid = tid >> 6, lane = tid & 63;
  const int wm = (wid >> 1) * 64, wn = (wid & 1) * 32;
  const int fr = lane & 15, fq = lane >> 4;
  float4v zf = {0.f, 0.f, 0.f, 0.f};
  float4v acc[4][2];
#pragma unroll
  for (int i = 0; i < 4; ++i) { acc[i][0] = zf; acc[i][1] = zf; }
  for (int k0 = 0; k0 < 256; k0 += 32) {
    *reinterpret_cast<uint4*>(&As[sr * LDA + sk]) = rA0;
    *reinterpret_cast<uint4*>(&As[(sr + 64) * LDA + sk]) = rA1;
    store_bf8(&Bs[sr * LDA + sk], rB0, rB1);
    if (k0 + 32 < 256) load_slice(k0 + 32);
    __syncthreads();
    short8 af[4], bf[2];
#pragma unroll
    for (int mi = 0; mi < 4; ++mi)
      af[mi] = *reinterpret_cast<const short8*>(&As[(wm + mi * 16 + fr) * LDA + fq * 8]);
#pragma unroll
    for (int nj = 0; nj < 2; ++nj)
      bf[nj] = *reinterpret_cast<const short8*>(&Bs[(wn + nj * 16 + fr) * LDA + fq * 8]);
#pragma unroll
    for (int mi = 0; mi < 4; ++mi)
#pragma unroll
      for (int nj = 0; nj < 2; ++nj)
        acc[mi][nj] = MFMA16(af[mi], bf[nj], acc[mi][nj], 0, 0, 0);
    __syncthreads();
  }
#pragma unroll
  for (int mi = 0; mi < 4; ++mi)
#pragma unroll
    for (int r = 0; r < 4; ++r) {
      int m = m0 + wm + mi * 16 + fq * 4 + r;
#pragma unroll
      for (int nj = 0; nj < 2; ++nj)
        D[(long)m * ldd + n0 + wn + nj * 16 + fr] = f2bf(acc[mi][nj][r]);
    }
}

// ---------------------------------------------------------------------------
// DENSE t1 GEMM + scatter epilogue.
// C[2048][4096] = x @ b1t^T; each 128x128 tile writes only rows routed to
// this tile's expert, into compact t1[row][512]. Tile 128x128, BK=64,
// register prefetch. grid = (32, 16)
// ---------------------------------------------------------------------------
__global__ __launch_bounds__(256, 2) void k_t1d(
    const float* __restrict__ x, const unsigned short* __restrict__ b1t,
    unsigned short* __restrict__ t1, const int* __restrict__ et,
    const int* __restrict__ rowmap)
{
  __shared__ __align__(16) unsigned short As[128 * LDK];
  __shared__ __align__(16) unsigned short Bs[128 * LDK];
  const int tid = threadIdx.x;
  const int m0 = blockIdx.y * 128;
  const int nb = blockIdx.x;                 // 0..31
  const int sr = tid >> 2, sk16 = (tid & 3) * 16;
  const float* A0 = x + (long)(m0 + sr) * cH + sk16;
  const float* A1 = A0 + (long)64 * cH;
  const unsigned short* B0 = b1t + (long)(nb * 128 + sr) * cH + sk16;
  const unsigned short* B1 = B0 + (long)64 * cH;
  float4 ra0[4], ra1[4];
  uint4  rb0[2], rb1[2];
  auto load_slice = [&](int k0) {
#pragma unroll
    for (int i = 0; i < 4; ++i) {
      ra0[i] = *reinterpret_cast<const float4*>(A0 + k0 + i * 4);
      ra1[i] = *reinterpret_cast<const float4*>(A1 + k0 + i * 4);
    }
#pragma unroll
    for (int i = 0; i < 2; ++i) {
      rb0[i] = *reinterpret_cast<const uint4*>(B0 + k0 + i * 8);
      rb1[i] = *reinterpret_cast<const uint4*>(B1 + k0 + i * 8);
    }
  };
  load_slice(0);
  const int wid = tid >> 6, lane = tid & 63;
  const int wm = (wid >> 1) * 64, wn = (wid & 1) * 64;
  const int fr = lane & 15, fq = lane >> 4;
  float4v zf = {0.f, 0.f, 0.f, 0.f};
  float4v acc[4][4];
#pragma unroll
  for (int i = 0; i < 4; ++i)
#pragma unroll
    for (int j = 0; j < 4; ++j) acc[i][j] = zf;
  for (int k0 = 0; k0 < cH; k0 += 64) {
    store_bf8(&As[sr * LDK + sk16], ra0[0], ra0[1]);
    store_bf8(&As[sr * LDK + sk16 + 8], ra0[2], ra0[3]);
    store_bf8(&As[(sr + 64) * LDK + sk16], ra1[0], ra1[1]);
    store_bf8(&As[(sr + 64) * LDK + sk16 + 8], ra1[2], ra1[3]);
    *reinterpret_cast<uint4*>(&Bs[sr * LDK + sk16]) = rb0[0];
    *reinterpret_cast<uint4*>(&Bs[sr * LDK + sk16 + 8]) = rb0[1];
    *reinterpret_cast<uint4*>(&Bs[(sr + 64) * LDK + sk16]) = rb1[0];
    *reinterpret_cast<uint4*>(&Bs[(sr + 64) * LDK + sk16 + 8]) = rb1[1];
    if (k0 + 64 < cH) load_slice(k0 + 64);
    __syncthreads();
#pragma unroll
    for (int ks = 0; ks < 2; ++ks) {
      short8 af[4], bf[4];
#pragma unroll
      for (int mi = 0; mi < 4; ++mi)
        af[mi] = *reinterpret_cast<const short8*>(
            &As[(wm + mi * 16 + fr) * LDK + ks * 32 + fq * 8]);
#pragma unroll
      for (int nj = 0; nj < 4; ++nj)
        bf[nj] = *reinterpret_cast<const short8*>(
            &Bs[(wn + nj * 16 + fr) * LDK + ks * 32 + fq * 8]);
#pragma unroll
      for (int mi = 0; mi < 4; ++mi)
#pragma unroll
        for (int nj = 0; nj < 4; ++nj)
          acc[mi][nj] = MFMA16(af[mi], bf[nj], acc[mi][nj], 0, 0, 0);
    }
    __syncthreads();
  }
  const int e_t = nb >> 2;
  const int colbase = (nb & 3) * 128 + wn;
#pragma unroll
  for (int mi = 0; mi < 4; ++mi)
#pragma unroll
    for (int r = 0; r < 4; ++r) {
      int t = m0 + wm + mi * 16 + fq * 4 + r;
      int crow = -1;
      if (et[2 * t] == e_t) crow = rowmap[2 * t];
      else if (et[2 * t + 1] == e_t) crow = rowmap[2 * t + 1];
      if (crow >= 0) {
#pragma unroll
        for (int nj = 0; nj < 4; ++nj)
          t1[(long)crow * 512 + colbase + nj * 16 + fr] = f2bf(acc[mi][nj][r]);
      }
    }
}

// ---------------------------------------------------------------------------
// dual GEMM: a = silu(t1g @ vgT^T) * (t1u @ vuT^T)  [rows x F], K=256
// tile 128x64, BK=32, register prefetch.  grid = (44, 16, E)
// ---------------------------------------------------------------------------
__global__ __launch_bounds__(256, 2) void k_act(
    const unsigned short* __restrict__ t1,
    const unsigned short* __restrict__ vgT, const unsigned short* __restrict__ vuT,
    unsigned short* __restrict__ a, const int* __restrict__ cnt,
    const int* __restrict__ off)
{
  __shared__ __align__(16) unsigned short Ag[128 * LDA], Au[128 * LDA];
  __shared__ __align__(16) unsigned short Bg[64 * LDA],  Bu[64 * LDA];
  const int e = blockIdx.z, c = cnt[e], o = off[e];
  const int m0 = blockIdx.y * 128;
  if (m0 >= c) return;
  const int n0 = blockIdx.x * 64;
  const int tid = threadIdx.x;
  const int sr = tid >> 2, sk = (tid & 3) * 8;
  const unsigned short* ar0 = (m0 + sr < c)      ? t1 + (long)(o + m0 + sr) * 512 + sk      : nullptr;
  const unsigned short* ar1 = (m0 + 64 + sr < c) ? t1 + (long)(o + m0 + 64 + sr) * 512 + sk : nullptr;
  const unsigned short* Btg = vgT + (long)e * cF * 256 + (long)(n0 + sr) * 256 + sk;
  const unsigned short* Btu = vuT + (long)e * cF * 256 + (long)(n0 + sr) * 256 + sk;
  const uint4 zu = make_uint4(0u, 0u, 0u, 0u);
  uint4 rg0, ru0, rg1, ru1, rbg, rbu;
  auto load_slice = [&](int k0) {
    rg0 = ar0 ? *reinterpret_cast<const uint4*>(ar0 + k0)       : zu;
    ru0 = ar0 ? *reinterpret_cast<const uint4*>(ar0 + 256 + k0) : zu;
    rg1 = ar1 ? *reinterpret_cast<const uint4*>(ar1 + k0)       : zu;
    ru1 = ar1 ? *reinterpret_cast<const uint4*>(ar1 + 256 + k0) : zu;
    rbg = *reinterpret_cast<const uint4*>(Btg + k0);
    rbu = *reinterpret_cast<const uint4*>(Btu + k0);
  };
  load_slice(0);
  const int wid = tid >> 6, lane = tid & 63;
  const int wm = (wid >> 1) * 64, wn = (wid & 1) * 32;
  const int fr = lane & 15, fq = lane >> 4;
  float4v zf = {0.f, 0.f, 0.f, 0.f};
  float4v accg[4][2], accu[4][2];
#pragma unroll
  for (int i = 0; i < 4; ++i) { accg[i][0] = zf; accg[i][1] = zf; accu[i][0] = zf; accu[i][1] = zf; }
  for (int k0 = 0; k0 < 256; k0 += 32) {
    *reinterpret_cast<uint4*>(&Ag[sr * LDA + sk]) = rg0;
    *reinterpret_cast<uint4*>(&Au[sr * LDA + sk]) = ru0;
    *reinterpret_cast<uint4*>(&Ag[(sr + 64) * LDA + sk]) = rg1;
    *reinterpret_cast<uint4*>(&Au[(sr + 64) * LDA + sk]) = ru1;
    *reinterpret_cast<uint4*>(&Bg[sr * LDA + sk]) = rbg;
    *reinterpret_cast<uint4*>(&Bu[sr * LDA + sk]) = rbu;
    if (k0 + 32 < 256) load_slice(k0 + 32);
    __syncthreads();
    short8 ag[4], au[4], bg[2], bu[2];
#pragma unroll
    for (int mi = 0; mi < 4; ++mi) {
      ag[mi] = *reinterpret_cast<const short8*>(&Ag[(wm + mi * 16 + fr) * LDA + fq * 8]);
      au[mi] = *reinterpret_cast<const short8*>(&Au[(wm + mi * 16 + fr) * LDA + fq * 8]);
    }
#pragma unroll
    for (int nj = 0; nj < 2; ++nj) {
      bg[nj] = *reinterpret_cast<const short8*>(&Bg[(wn + nj * 16 + fr) * LDA + fq * 8]);
      bu[nj] = *reinterpret_cast<const short8*>(&Bu[(wn + nj * 16 + fr) * LDA + fq * 8]);
    }
#pragma unroll
    for (int mi = 0; mi < 4; ++mi)
#pragma unroll
      for (int nj = 0; nj < 2; ++nj) {
        accg[mi][nj] = MFMA16(ag[mi], bg[nj], accg[mi][nj], 0, 0, 0);
        accu[mi][nj] = MFMA16(au[mi], bu[nj], accu[mi][nj], 0, 0, 0);
      }
    __syncthreads();
  }
#pragma unroll
  for (int mi = 0; mi < 4; ++mi)
#pragma unroll
    for (int r = 0; r < 4; ++r) {
      int row = m0 + wm + mi * 16 + fq * 4 + r;
      if (row < c) {
#pragma unroll
        for (int nj = 0; nj < 2; ++nj) {
          float g = accg[mi][nj][r];
          float u = accu[mi][nj][r];
          float s = g / (1.f + expf(-g)) * u;
          a[(long)(o + row) * cF + n0 + wn + nj * 16 + fr] = f2bf(s);
        }
      }
    }
}

// ---------------------------------------------------------------------------
// t3p[ks] = a @ udT^T (split-K=4, plain fp32 stores).  [4][ROWS][256].
// r2-proven inline staging (NO manual reg-prefetch, NO min-wave cap: the
// (256,4) cap at r3/r4 forced VGPR=32 and the compiler deleted the prefetch
// -> ~9 us/iter; inline at free VGPR ran ~2 us/iter).
// tile 64x64, BK=64, 11 iters. grid = (16, 32, E): x = n(0..3) | ksp(0..3)<<2
// ---------------------------------------------------------------------------
__global__ __launch_bounds__(256) void k_t3(
    const unsigned short* __restrict__ a, const unsigned short* __restrict__ udT,
    float* __restrict__ t3p, const int* __restrict__ cnt,
    const int* __restrict__ off)
{
  __shared__ __align__(16) unsigned short As[64 * LDK], Bs[64 * LDK];
  const int e = blockIdx.z, c = cnt[e], o = off[e];
  const int m0 = blockIdx.y * 64;
  if (m0 >= c) return;
  const int n0 = (blockIdx.x & 3) * 64;
  const int ksp = blockIdx.x >> 2;                 // 0..3
  const int kbase = ksp * 704, kend = kbase + 704;
  const int tid = threadIdx.x;
  const int sr = tid >> 2, sk16 = (tid & 3) * 16;
  const unsigned short* arow = (m0 + sr < c)
      ? a + (long)(o + m0 + sr) * cF + sk16 : nullptr;
  const unsigned short* brow = udT + (long)e * 256 * cF + (long)(n0 + sr) * cF + sk16;
  const uint4 zu = make_uint4(0u, 0u, 0u, 0u);
  const int wid = tid >> 6, lane = tid & 63;
  const int wm = (wid >> 1) * 32, wn = (wid & 1) * 32;
  const int fr = lane & 15, fq = lane >> 4;
  float4v zf = {0.f, 0.f, 0.f, 0.f};
  float4v acc[2][2] = {{zf, zf}, {zf, zf}};
  for (int k0 = kbase; k0 < kend; k0 += 64) {
    uint4 a0 = arow ? *reinterpret_cast<const uint4*>(arow + k0)     : zu;
    uint4 a1 = arow ? *reinterpret_cast<const uint4*>(arow + k0 + 8) : zu;
    uint4 b0 = *reinterpret_cast<const uint4*>(brow + k0);
    uint4 b1 = *reinterpret_cast<const uint4*>(brow + k0 + 8);
    *reinterpret_cast<uint4*>(&As[sr * LDK + sk16])     = a0;
    *reinterpret_cast<uint4*>(&As[sr * LDK + sk16 + 8]) = a1;
    *reinterpret_cast<uint4*>(&Bs[sr * LDK + sk16])     = b0;
    *reinterpret_cast<uint4*>(&Bs[sr * LDK + sk16 + 8]) = b1;
    __syncthreads();
#pragma unroll
    for (int ks = 0; ks < 2; ++ks) {
      short8 af[2], bf[2];
#pragma unroll
      for (int mi = 0; mi < 2; ++mi)
        af[mi] = *reinterpret_cast<const short8*>(
            &As[(wm + mi * 16 + fr) * LDK + ks * 32 + fq * 8]);
#pragma unroll
      for (int nj = 0; nj < 2; ++nj)
        bf[nj] = *reinterpret_cast<const short8*>(
            &Bs[(wn + nj * 16 + fr) * LDK + ks * 32 + fq * 8]);
#pragma unroll
      for (int mi = 0; mi < 2; ++mi)
#pragma unroll
        for (int nj = 0; nj < 2; ++nj)
          acc[mi][nj] = MFMA16(af[mi], bf[nj], acc[mi][nj], 0, 0, 0);
    }
    __syncthreads();
  }
  float* dstbase = t3p + (long)ksp * ROWS * 256;
#pragma unroll
  for (int mi = 0; mi < 2; ++mi)
#pragma unroll
    for (int r = 0; r < 4; ++r) {
      int row = m0 + wm + mi * 16 + fq * 4 + r;
      if (row < c) {
        float* dst = dstbase + (long)(o + row) * 256 + n0 + wn;
#pragma unroll
        for (int nj = 0; nj < 2; ++nj)
          dst[nj * 16 + fr] = acc[mi][nj][r];
      }
    }
}

// ---------------------------------------------------------------------------
// y = (sum of 4 t3p partials) @ vd2t^T   [rows x 1024] bf16, plain stores.
// K = 256; partials summed in-register during staging. tile 128x64, BK=32.
// grid = (16, 16, E)
// ---------------------------------------------------------------------------
__global__ __launch_bounds__(256, 2) void k_y(
    const float* __restrict__ t3p, const unsigned short* __restrict__ vd2t,
    unsigned short* __restrict__ y, const int* __restrict__ cnt,
    const int* __restrict__ off)
{
  __shared__ __align__(16) unsigned short As[128 * LDA], Bs[64 * LDA];
  const int e = blockIdx.z, c = cnt[e], o = off[e];
  const int m0 = blockIdx.y * 128;
  if (m0 >= c) return;
  const int n0 = blockIdx.x * 64;
  const int tid = threadIdx.x;
  const int sr = tid >> 2, sk = (tid & 3) * 8;
  const long psz = (long)ROWS * 256;
  const float* ar0 = (m0 + sr < c)      ? t3p + (long)(o + m0 + sr) * 256 + sk      : nullptr;
  const float* ar1 = (m0 + 64 + sr < c) ? t3p + (long)(o + m0 + 64 + sr) * 256 + sk : nullptr;
  const unsigned short* brow = vd2t + (long)e * cH * 256 + (long)(n0 + sr) * 256 + sk;
  const float4 z4 = make_float4(0.f, 0.f, 0.f, 0.f);
  float4 rA0[2], rA1[2];
  uint4 rB;
  auto sum4 = [&](const float* p, int k0) {
    float4 s = *reinterpret_cast<const float4*>(p + k0);
#pragma unroll
    for (int q = 1; q < 4; ++q) {
      float4 t = *reinterpret_cast<const float4*>(p + (long)q * psz + k0);
      s.x += t.x; s.y += t.y; s.z += t.z; s.w += t.w;
    }
    return s;
  };
  auto load_slice = [&](int k0) {
    rA0[0] = ar0 ? sum4(ar0, k0)     : z4;
    rA0[1] = ar0 ? sum4(ar0, k0 + 4) : z4;
    rA1[0] = ar1 ? sum4(ar1, k0)     : z4;
    rA1[1] = ar1 ? sum4(ar1, k0 + 4) : z4;
    rB = *reinterpret_cast<const uint4*>(brow + k0);
  };
  load_slice(0);
  const int wid = tid >> 6, lane = tid & 63;
  const int wm = (wid >> 1) * 64, wn = (wid & 1) * 32;
  const int fr = lane & 15, fq = lane >> 4;
  float4v zf = {0.f, 0.f, 0.f, 0.f};
  float4v acc[4][2];
#pragma unroll
  for (int i = 0; i < 4; ++i) { acc[i][0] = zf; acc[i][1] = zf; }
  for (int k0 = 0; k0 < 256; k0 += 32) {
    store_bf8(&As[sr * LDA + sk], rA0[0], rA0[1]);
    store_bf8(&As[(sr + 64) * LDA + sk], rA1[0], rA1[1]);
    *reinterpret_cast<uint4*>(&Bs[sr * LDA + sk]) = rB;
    if (k0 + 32 < 256) load_slice(k0 + 32);
    __syncthreads();
    short8 af[4], bf[2];
#pragma unroll
    for (int mi = 0; mi < 4; ++mi)
      af[mi] = *reinterpret_cast<const short8*>(&As[(wm + mi * 16 + fr) * LDA + fq * 8]);
#pragma unroll
    for (int nj = 0; nj < 2; ++nj)
      bf[nj] = *reinterpret_cast<const short8*>(&Bs[(wn + nj * 16 + fr) * LDA + fq * 8]);
#pragma unroll
    for (int mi = 0; mi < 4; ++mi)
#pragma unroll
      for (int nj = 0; nj < 2; ++nj)
        acc[mi][nj] = MFMA16(af[mi], bf[nj], acc[mi][nj], 0, 0, 0);
    __syncthreads();
  }
#pragma unroll
  for (int mi = 0; mi < 4; ++mi)
#pragma unroll
    for (int r = 0; r < 4; ++r) {
      int row = m0 + wm + mi * 16 + fq * 4 + r;
      if (row < c) {
#pragma unroll
        for (int nj = 0; nj < 2; ++nj)
          y[(long)(o + row) * cH + n0 + wn + nj * 16 + fr] = f2bf(acc[mi][nj][r]);
      }
    }
}

// ---------------------------------------------------------------------------
// out[t] = w0 * y[rowmap[2t]] + w1 * y[rowmap[2t+1]]   (pure write, no zero)
// ---------------------------------------------------------------------------
__global__ __launch_bounds__(256) void k_combine(
    const unsigned short* __restrict__ y, const float* __restrict__ wt,
    const int* __restrict__ rowmap, float* __restrict__ out)
{
  const int tid = threadIdx.x;
  const int t = blockIdx.x * 2 + (tid >> 7);
  const int h = (tid & 127) * 8;
  const int r0 = rowmap[2 * t], r1 = rowmap[2 * t + 1];
  const float w0 = wt[2 * t], w1 = wt[2 * t + 1];
  union { uint4 v; unsigned short s[8]; } ua, ub;
  ua.v = *reinterpret_cast<const uint4*>(y + (long)r0 * cH + h);
  ub.v = *reinterpret_cast<const uint4*>(y + (long)r1 * cH + h);
  float o[8];
#pragma unroll
  for (int i = 0; i < 8; ++i)
    o[i] = w0 * bf2f(ua.s[i]) + w1 * bf2f(ub.s[i]);
  float* dst = out + (long)t * cH + h;
  *reinterpret_cast<float4*>(dst)     = make_float4(o[0], o[1], o[2], o[3]);
  *reinterpret_cast<float4*>(dst + 4) = make_float4(o[4], o[5], o[6], o[7]);
}

// ---------------------------------------------------------------------------
extern "C" void kernel_launch(void* const* d_in, const int* in_sizes, int n_in,
                              void* d_out, int out_size, void* d_ws, size_t ws_size,
                              hipStream_t stream)
{
  const float* x  = (const float*)d_in[0];
  const float* gw = (const float*)d_in[1];
  const float* Ug = (const float*)d_in[2];
  const float* Cg = (const float*)d_in[3];
  const float* Vg = (const float*)d_in[4];
  const float* Uu = (const float*)d_in[5];
  const float* Cu = (const float*)d_in[6];
  const float* Vu = (const float*)d_in[7];
  const float* Ud = (const float*)d_in[8];
  const float* Cd = (const float*)d_in[9];
  const float* Vd = (const float*)d_in[10];
  float* out = (float*)d_out;

  // workspace layout (~79 MiB peak, with aliasing)
  char* w = (char*)d_ws;
  // [vgT 11.53 | b1t 8.39] phase-1; t3p (16.78, fp32 x4 partials) aliases both
  unsigned short* vgT = (unsigned short*)w;
  float*          t3p = (float*)w;           w += (long)cE * cF * 256 * 2;    // 11.53
  unsigned short* b1t = (unsigned short*)w;  w += (long)cE * 512 * 1024 * 2;  // 8.39
  unsigned short* vd2t = (unsigned short*)w; w += (long)cE * cH * 256 * 2;    // 4.19
  // vuT phase-1; yb (8.39) aliases it in phase 2
  unsigned short* vuT = (unsigned short*)w;
  unsigned short* yb  = (unsigned short*)w;  w += (long)cE * cF * 256 * 2;    // 11.53
  unsigned short* udT = (unsigned short*)w;  w += (long)cE * 256 * cF * 2;    // 11.53
  unsigned short* VdT = (unsigned short*)w;  w += (long)cE * cH * 256 * 2;    // 4.19
  unsigned short* CgT = (unsigned short*)w;  w += (long)cR * cR * 2;          // 0.13
  unsigned short* CuT = (unsigned short*)w;  w += (long)cR * cR * 2;          // 0.13
  unsigned short* t1  = (unsigned short*)w;  w += (long)ROWS * 512 * 2;       // 4.19
  unsigned short* ab  = (unsigned short*)w;  w += (long)ROWS * cF * 2;        // 23.07
  float* wt   = (float*)w; w += ROWS * 4;
  int* et     = (int*)w; w += ROWS * 4;
  int* rowmap = (int*)w; w += ROWS * 4;
  int* cnt = (int*)w; w += cE * 4;
  int* off = (int*)w; w += cE * 4;

  // 1. gating + lists
  k_gating<<<dim3(cT / 256), dim3(256), 0, stream>>>(x, gw, et, wt);
  k_lists<<<dim3(1), dim3(256), 0, stream>>>(et, rowmap, cnt, off);
  // 2. transposes (fp32 -> bf16)
  k_tconv<<<dim3(cR / 32, cR / 32, 1), dim3(256), 0, stream>>>(Cg, CgT, cR, cR);
  k_tconv<<<dim3(cR / 32, cR / 32, 1), dim3(256), 0, stream>>>(Cu, CuT, cR, cR);
  k_tconv<<<dim3(cH / 32, cR / 32, cE), dim3(256), 0, stream>>>(Vd, VdT, cR, cH);
  k_tconv<<<dim3(cF / 32, cR / 32, cE), dim3(256), 0, stream>>>(Vg, vgT, cR, cF);
  k_tconv<<<dim3(cF / 32, cR / 32, cE), dim3(256), 0, stream>>>(Vu, vuT, cR, cF);
  k_tconv<<<dim3(cR / 32, cF / 32, cE), dim3(256), 0, stream>>>(Ud, udT, cF, cR);
  // 3. MFMA folds (all K=256)
  k_foldm<<<dim3(cH / 64, cR / 128, cE), dim3(256), 0, stream>>>(
      CgT, 0, Ug, (long)cH * cR, b1t, (long)512 * 1024, cH);
  k_foldm<<<dim3(cH / 64, cR / 128, cE), dim3(256), 0, stream>>>(
      CuT, 0, Uu, (long)cH * cR, b1t + (long)256 * 1024, (long)512 * 1024, cH);
  k_foldm<<<dim3(cR / 64, cH / 128, cE), dim3(256), 0, stream>>>(
      VdT, (long)cH * cR, Cd, 0, vd2t, (long)cH * 256, cR);
  // 4. dense t1 GEMM + scatter into compact rows
  k_t1d<<<dim3(32, cT / 128), dim3(256), 0, stream>>>(x, b1t, t1, et, rowmap);
  // 5. a = silu(t1g @ Vg) * (t1u @ Vu)
  k_act<<<dim3(cF / 64, cT / 128, cE), dim3(256), 0, stream>>>(t1, vgT, vuT, ab, cnt, off);
  // 6. t3p = a @ Ud (split-K=4, plain stores; aliases dead vgT+b1t)
  k_t3<<<dim3(16, cT / 64, cE), dim3(256), 0, stream>>>(ab, udT, t3p, cnt, off);
  // 7. y = (sum t3p) @ Vd2 (plain bf16 stores; aliases dead vuT)
  k_y<<<dim3(cH / 64, cT / 128, cE), dim3(256), 0, stream>>>(t3p, vd2t, yb, cnt, off);
  // 8. out = w0*y[r0] + w1*y[r1]
  k_combine<<<dim3(cT / 2), dim3(256), 0, stream>>>(yb, wt, rowmap, out);
}

// Round 6
// 386.234 us; speedup vs baseline: 1.4522x; 1.0928x over previous
//
#include <hip/hip_runtime.h>
#include <math.h>

constexpr int cE = 8;
constexpr int cH = 1024;
constexpr int cF = 2816;
constexpr int cR = 256;
constexpr int cT = 2048;
constexpr int ROWS = cT * 2;   // total routed (token, expert) rows = T*K
constexpr int LDA = 40;        // padded LDS row stride (BK=32 reg-staged kernels)
constexpr int LDK = 72;        // padded LDS row stride (BK=64 reg-staged kernels)

using short8  = __attribute__((ext_vector_type(8))) short;
using float4v = __attribute__((ext_vector_type(4))) float;
#define MFMA16 __builtin_amdgcn_mfma_f32_16x16x32_bf16

__device__ __forceinline__ unsigned short f2bf(float f) {
  union { float f; unsigned u; } v; v.f = f;
  unsigned r = v.u + 0x7fffu + ((v.u >> 16) & 1u);   // RNE
  return (unsigned short)(r >> 16);
}
__device__ __forceinline__ float bf2f(unsigned short s) {
  union { unsigned u; float f; } v; v.u = (unsigned)s << 16; return v.f;
}

// pack 8 fp32 -> 8 bf16, single 16B store
__device__ __forceinline__ void store_bf8(unsigned short* dst, float4 a, float4 b) {
  union { unsigned short u[8]; uint4 v; } t;
  t.u[0] = f2bf(a.x); t.u[1] = f2bf(a.y); t.u[2] = f2bf(a.z); t.u[3] = f2bf(a.w);
  t.u[4] = f2bf(b.x); t.u[5] = f2bf(b.y); t.u[6] = f2bf(b.z); t.u[7] = f2bf(b.w);
  *reinterpret_cast<uint4*>(dst) = t.v;
}

// async global->LDS, 16 B per lane. LDS dest = wave-uniform base + lane*16
// (m104/m108): the lane's global address must be the element that belongs at
// that LDS slot.
__device__ __forceinline__ void gld16(const unsigned short* g, unsigned short* l) {
  __builtin_amdgcn_global_load_lds(
      (const __attribute__((address_space(1))) void*)g,
      (__attribute__((address_space(3))) void*)l, 16, 0, 0);
}

// ---------------------------------------------------------------------------
// gating: logits = x @ gate_w, top-2, renormalized weights
// ---------------------------------------------------------------------------
__global__ __launch_bounds__(256) void k_gating(
    const float* __restrict__ x, const float* __restrict__ gw,
    int* __restrict__ et, float* __restrict__ wt)
{
  __shared__ float gws[cH * cE];
  const int tid = threadIdx.x;
  for (int i = tid; i < cH * cE; i += 256) gws[i] = gw[i];
  __syncthreads();
  const int t = blockIdx.x * 256 + tid;
  const float4* xr = reinterpret_cast<const float4*>(x + (long)t * cH);
  float l[cE];
#pragma unroll
  for (int e = 0; e < cE; ++e) l[e] = 0.f;
  for (int h4 = 0; h4 < cH / 4; ++h4) {
    float4 v = xr[h4];
    const float* g0 = &gws[(h4 * 4 + 0) * cE];
    const float* g1 = &gws[(h4 * 4 + 1) * cE];
    const float* g2 = &gws[(h4 * 4 + 2) * cE];
    const float* g3 = &gws[(h4 * 4 + 3) * cE];
#pragma unroll
    for (int e = 0; e < cE; ++e)
      l[e] += v.x * g0[e] + v.y * g1[e] + v.z * g2[e] + v.w * g3[e];
  }
  int i0 = 0; float m0 = l[0];
#pragma unroll
  for (int e = 1; e < cE; ++e) if (l[e] > m0) { m0 = l[e]; i0 = e; }
  int i1 = -1; float m1 = -1e30f;
#pragma unroll
  for (int e = 0; e < cE; ++e) if (e != i0 && l[e] > m1) { m1 = l[e]; i1 = e; }
  float w0 = 1.f / (1.f + expf(m1 - m0));
  et[t * 2 + 0] = i0;  et[t * 2 + 1] = i1;
  wt[t * 2 + 0] = w0;  wt[t * 2 + 1] = 1.f - w0;
}

// ---------------------------------------------------------------------------
// build compact per-expert token lists + inverse map (single block)
// ---------------------------------------------------------------------------
__global__ __launch_bounds__(256) void k_lists(
    const int* __restrict__ et, int* __restrict__ rowmap,
    int* __restrict__ cnt, int* __restrict__ off)
{
  __shared__ int c[cE], p[cE], o[cE];
  const int tid = threadIdx.x;
  if (tid < cE) { c[tid] = 0; p[tid] = 0; }
  __syncthreads();
  for (int i = tid; i < ROWS; i += 256) atomicAdd(&c[et[i]], 1);
  __syncthreads();
  if (tid == 0) {
    int s = 0;
    for (int e = 0; e < cE; ++e) { o[e] = s; s += c[e]; }
  }
  __syncthreads();
  for (int i = tid; i < ROWS; i += 256) {
    int e = et[i];
    int slot = atomicAdd(&p[e], 1);
    rowmap[i] = o[e] + slot;
  }
  if (tid < cE) { cnt[tid] = c[tid]; off[tid] = o[tid]; }
}

// ---------------------------------------------------------------------------
// transpose + fp32->bf16: in [P][Q] per batch -> out [Q][P] per batch
// ---------------------------------------------------------------------------
__global__ __launch_bounds__(256) void k_tconv(
    const float* __restrict__ in, unsigned short* __restrict__ out, int P, int Q)
{
  __shared__ float tile[32][33];
  const long es = (long)P * Q;
  const int e = blockIdx.z;
  in += e * es; out += e * es;
  const int c0 = blockIdx.x * 32, r0 = blockIdx.y * 32;
  const int tid = threadIdx.x;
  const int r = tid >> 3, c4 = (tid & 7) * 4;
  float4 v = *reinterpret_cast<const float4*>(in + (long)(r0 + r) * Q + c0 + c4);
  tile[r][c4 + 0] = v.x; tile[r][c4 + 1] = v.y;
  tile[r][c4 + 2] = v.z; tile[r][c4 + 3] = v.w;
  __syncthreads();
  const int cc = tid >> 3, rr4 = (tid & 7) * 4;
  ushort4 o;
  o.x = f2bf(tile[rr4 + 0][cc]);
  o.y = f2bf(tile[rr4 + 1][cc]);
  o.z = f2bf(tile[rr4 + 2][cc]);
  o.w = f2bf(tile[rr4 + 3][cc]);
  *reinterpret_cast<ushort4*>(out + (long)(c0 + cc) * P + r0 + rr4) = o;
}

// ---------------------------------------------------------------------------
// x fp32 -> xb bf16 (flat).  grid = T*H/(8*256)
// ---------------------------------------------------------------------------
__global__ __launch_bounds__(256) void k_xconv(
    const float* __restrict__ x, unsigned short* __restrict__ xb)
{
  long i = ((long)blockIdx.x * 256 + threadIdx.x) * 8;
  float4 a = *reinterpret_cast<const float4*>(x + i);
  float4 b = *reinterpret_cast<const float4*>(x + i + 4);
  store_bf8(xb + i, a, b);
}

// ---------------------------------------------------------------------------
// MFMA fold: D[m][n] = sum_k A[m][k] * B[n][k],  K = 256 fixed.
// tile 128x64, BK=32, register prefetch. grid = (N/64, M/128, E)
// ---------------------------------------------------------------------------
__global__ __launch_bounds__(256, 2) void k_foldm(
    const unsigned short* __restrict__ A, long sA,
    const float* __restrict__ B, long sB,
    unsigned short* __restrict__ D, long sD, int ldd)
{
  __shared__ __align__(16) unsigned short As[128 * LDA], Bs[64 * LDA];
  const int e = blockIdx.z;
  A += e * sA; B += e * sB; D += e * sD;
  const int m0 = blockIdx.y * 128, n0 = blockIdx.x * 64;
  const int tid = threadIdx.x;
  const int sr = tid >> 2, sk = (tid & 3) * 8;
  const unsigned short* a0 = A + (long)(m0 + sr) * 256 + sk;
  const unsigned short* a1 = a0 + (long)64 * 256;
  const float* br = B + (long)(n0 + sr) * 256 + sk;
  uint4 rA0, rA1; float4 rB0, rB1;
  auto load_slice = [&](int k0) {
    rA0 = *reinterpret_cast<const uint4*>(a0 + k0);
    rA1 = *reinterpret_cast<const uint4*>(a1 + k0);
    rB0 = *reinterpret_cast<const float4*>(br + k0);
    rB1 = *reinterpret_cast<const float4*>(br + k0 + 4);
  };
  load_slice(0);
  const int wid = tid >> 6, lane = tid & 63;
  const int wm = (wid >> 1) * 64, wn = (wid & 1) * 32;
  const int fr = lane & 15, fq = lane >> 4;
  float4v zf = {0.f, 0.f, 0.f, 0.f};
  float4v acc[4][2];
#pragma unroll
  for (int i = 0; i < 4; ++i) { acc[i][0] = zf; acc[i][1] = zf; }
  for (int k0 = 0; k0 < 256; k0 += 32) {
    *reinterpret_cast<uint4*>(&As[sr * LDA + sk]) = rA0;
    *reinterpret_cast<uint4*>(&As[(sr + 64) * LDA + sk]) = rA1;
    store_bf8(&Bs[sr * LDA + sk], rB0, rB1);
    if (k0 + 32 < 256) load_slice(k0 + 32);
    __syncthreads();
    short8 af[4], bf[2];
#pragma unroll
    for (int mi = 0; mi < 4; ++mi)
      af[mi] = *reinterpret_cast<const short8*>(&As[(wm + mi * 16 + fr) * LDA + fq * 8]);
#pragma unroll
    for (int nj = 0; nj < 2; ++nj)
      bf[nj] = *reinterpret_cast<const short8*>(&Bs[(wn + nj * 16 + fr) * LDA + fq * 8]);
#pragma unroll
    for (int mi = 0; mi < 4; ++mi)
#pragma unroll
      for (int nj = 0; nj < 2; ++nj)
        acc[mi][nj] = MFMA16(af[mi], bf[nj], acc[mi][nj], 0, 0, 0);
    __syncthreads();
  }
#pragma unroll
  for (int mi = 0; mi < 4; ++mi)
#pragma unroll
    for (int r = 0; r < 4; ++r) {
      int m = m0 + wm + mi * 16 + fq * 4 + r;
#pragma unroll
      for (int nj = 0; nj < 2; ++nj)
        D[(long)m * ldd + n0 + wn + nj * 16 + fr] = f2bf(acc[mi][nj][r]);
    }
}

// ---------------------------------------------------------------------------
// DENSE t1 GEMM + scatter epilogue — m97-style async staging.
// C[2048][4096] = xb @ b1t^T (both bf16, K-contiguous); each 128x128 tile
// writes only rows routed to this tile's expert into compact t1[row][512].
// BK=64, unpadded LDS [128][64], global_load_lds width 16. grid = (32, 16)
// ---------------------------------------------------------------------------
__global__ __launch_bounds__(256, 2) void k_t1d(
    const unsigned short* __restrict__ xb, const unsigned short* __restrict__ b1t,
    unsigned short* __restrict__ t1, const int* __restrict__ et,
    const int* __restrict__ rowmap)
{
  __shared__ __align__(16) unsigned short As[128 * 64];
  __shared__ __align__(16) unsigned short Bs[128 * 64];
  const int tid = threadIdx.x;
  const int wid = tid >> 6, lane = tid & 63;
  const int m0 = blockIdx.y * 128;
  const int nb = blockIdx.x;                 // 0..31
  // staging: wave w call j covers tile rows w*32+j*8 .. +7; lane -> row
  // base+(lane>>3), col (lane&7)*8 — matches LDS base+lane*16B exactly.
  const int srow = wid * 32 + (lane >> 3);
  const int scol = (lane & 7) * 8;
  const unsigned short* gA = xb + (long)(m0 + srow) * cH + scol;
  const unsigned short* gB = b1t + (long)(nb * 128 + srow) * cH + scol;
  unsigned short* lA = As + wid * 32 * 64;   // wave-uniform
  unsigned short* lB = Bs + wid * 32 * 64;
  const int wm = (wid >> 1) * 64, wn = (wid & 1) * 64;
  const int fr = lane & 15, fq = lane >> 4;
  float4v zf = {0.f, 0.f, 0.f, 0.f};
  float4v acc[4][4];
#pragma unroll
  for (int i = 0; i < 4; ++i)
#pragma unroll
    for (int j = 0; j < 4; ++j) acc[i][j] = zf;
  for (int k0 = 0; k0 < cH; k0 += 64) {
#pragma unroll
    for (int j = 0; j < 4; ++j) {
      gld16(gA + k0 + (long)j * 8 * cH, lA + j * 8 * 64);
      gld16(gB + k0 + (long)j * 8 * cH, lB + j * 8 * 64);
    }
    __syncthreads();
#pragma unroll
    for (int ks = 0; ks < 2; ++ks) {
      short8 af[4], bf[4];
#pragma unroll
      for (int mi = 0; mi < 4; ++mi)
        af[mi] = *reinterpret_cast<const short8*>(
            &As[(wm + mi * 16 + fr) * 64 + ks * 32 + fq * 8]);
#pragma unroll
      for (int nj = 0; nj < 4; ++nj)
        bf[nj] = *reinterpret_cast<const short8*>(
            &Bs[(wn + nj * 16 + fr) * 64 + ks * 32 + fq * 8]);
#pragma unroll
      for (int mi = 0; mi < 4; ++mi)
#pragma unroll
        for (int nj = 0; nj < 4; ++nj)
          acc[mi][nj] = MFMA16(af[mi], bf[nj], acc[mi][nj], 0, 0, 0);
    }
    __syncthreads();
  }
  const int e_t = nb >> 2;
  const int colbase = (nb & 3) * 128 + wn;
#pragma unroll
  for (int mi = 0; mi < 4; ++mi)
#pragma unroll
    for (int r = 0; r < 4; ++r) {
      int t = m0 + wm + mi * 16 + fq * 4 + r;
      int crow = -1;
      if (et[2 * t] == e_t) crow = rowmap[2 * t];
      else if (et[2 * t + 1] == e_t) crow = rowmap[2 * t + 1];
      if (crow >= 0) {
#pragma unroll
        for (int nj = 0; nj < 4; ++nj)
          t1[(long)crow * 512 + colbase + nj * 16 + fr] = f2bf(acc[mi][nj][r]);
      }
    }
}

// ---------------------------------------------------------------------------
// dual GEMM: a = silu(t1g @ vgT^T) * (t1u @ vuT^T)  [rows x F], K=256
// async staging (global_load_lds), unpadded LDS, BK=32. grid = (44, 16, E)
// OOB A-rows read adjacent valid/poison bf16 (finite, discarded at store).
// ---------------------------------------------------------------------------
__global__ __launch_bounds__(256, 2) void k_act(
    const unsigned short* __restrict__ t1,
    const unsigned short* __restrict__ vgT, const unsigned short* __restrict__ vuT,
    unsigned short* __restrict__ a, const int* __restrict__ cnt,
    const int* __restrict__ off)
{
  __shared__ __align__(16) unsigned short Ag[128 * 32], Au[128 * 32];
  __shared__ __align__(16) unsigned short Bg[64 * 32],  Bu[64 * 32];
  const int e = blockIdx.z, c = cnt[e], o = off[e];
  const int m0 = blockIdx.y * 128;
  if (m0 >= c) return;
  const int n0 = blockIdx.x * 64;
  const int tid = threadIdx.x;
  const int wid = tid >> 6, lane = tid & 63;
  // staging lane map for 64B rows: 16 rows/call; row = base+(lane>>2),
  // col = (lane&3)*8
  const int sr16 = lane >> 2, sc = (lane & 3) * 8;
  const unsigned short* gAg = t1 + (long)(o + m0 + wid * 32 + sr16) * 512 + sc;
  const unsigned short* gAu = gAg + 256;
  const unsigned short* gBg = vgT + (long)e * cF * 256 + (long)(n0 + wid * 16 + sr16) * 256 + sc;
  const unsigned short* gBu = vuT + (long)e * cF * 256 + (long)(n0 + wid * 16 + sr16) * 256 + sc;
  unsigned short* lAg = Ag + wid * 32 * 32;
  unsigned short* lAu = Au + wid * 32 * 32;
  unsigned short* lBg = Bg + wid * 16 * 32;
  unsigned short* lBu = Bu + wid * 16 * 32;
  const int wm = (wid >> 1) * 64, wn = (wid & 1) * 32;
  const int fr = lane & 15, fq = lane >> 4;
  float4v zf = {0.f, 0.f, 0.f, 0.f};
  float4v accg[4][2], accu[4][2];
#pragma unroll
  for (int i = 0; i < 4; ++i) { accg[i][0] = zf; accg[i][1] = zf; accu[i][0] = zf; accu[i][1] = zf; }
  for (int k0 = 0; k0 < 256; k0 += 32) {
#pragma unroll
    for (int j = 0; j < 2; ++j) {
      gld16(gAg + (long)j * 16 * 512 + k0, lAg + j * 16 * 32);
      gld16(gAu + (long)j * 16 * 512 + k0, lAu + j * 16 * 32);
    }
    gld16(gBg + k0, lBg);
    gld16(gBu + k0, lBu);
    __syncthreads();
    short8 ag[4], au[4], bg[2], bu[2];
#pragma unroll
    for (int mi = 0; mi < 4; ++mi) {
      ag[mi] = *reinterpret_cast<const short8*>(&Ag[(wm + mi * 16 + fr) * 32 + fq * 8]);
      au[mi] = *reinterpret_cast<const short8*>(&Au[(wm + mi * 16 + fr) * 32 + fq * 8]);
    }
#pragma unroll
    for (int nj = 0; nj < 2; ++nj) {
      bg[nj] = *reinterpret_cast<const short8*>(&Bg[(wn + nj * 16 + fr) * 32 + fq * 8]);
      bu[nj] = *reinterpret_cast<const short8*>(&Bu[(wn + nj * 16 + fr) * 32 + fq * 8]);
    }
#pragma unroll
    for (int mi = 0; mi < 4; ++mi)
#pragma unroll
      for (int nj = 0; nj < 2; ++nj) {
        accg[mi][nj] = MFMA16(ag[mi], bg[nj], accg[mi][nj], 0, 0, 0);
        accu[mi][nj] = MFMA16(au[mi], bu[nj], accu[mi][nj], 0, 0, 0);
      }
    __syncthreads();
  }
#pragma unroll
  for (int mi = 0; mi < 4; ++mi)
#pragma unroll
    for (int r = 0; r < 4; ++r) {
      int row = m0 + wm + mi * 16 + fq * 4 + r;
      if (row < c) {
#pragma unroll
        for (int nj = 0; nj < 2; ++nj) {
          float g = accg[mi][nj][r];
          float u = accu[mi][nj][r];
          float s = g / (1.f + expf(-g)) * u;
          a[(long)(o + row) * cF + n0 + wn + nj * 16 + fr] = f2bf(s);
        }
      }
    }
}

// ---------------------------------------------------------------------------
// t3p[ks] = a @ udT^T (split-K=4, plain fp32 stores).  [4][ROWS][256].
// inline staging, NO min-wave cap (r4 lesson). tile 64x64, BK=64, 11 iters.
// grid = (16, 32, E): x = n(0..3) | ksp(0..3)<<2
// ---------------------------------------------------------------------------
__global__ __launch_bounds__(256) void k_t3(
    const unsigned short* __restrict__ a, const unsigned short* __restrict__ udT,
    float* __restrict__ t3p, const int* __restrict__ cnt,
    const int* __restrict__ off)
{
  __shared__ __align__(16) unsigned short As[64 * LDK], Bs[64 * LDK];
  const int e = blockIdx.z, c = cnt[e], o = off[e];
  const int m0 = blockIdx.y * 64;
  if (m0 >= c) return;
  const int n0 = (blockIdx.x & 3) * 64;
  const int ksp = blockIdx.x >> 2;                 // 0..3
  const int kbase = ksp * 704, kend = kbase + 704;
  const int tid = threadIdx.x;
  const int sr = tid >> 2, sk16 = (tid & 3) * 16;
  const unsigned short* arow = (m0 + sr < c)
      ? a + (long)(o + m0 + sr) * cF + sk16 : nullptr;
  const unsigned short* brow = udT + (long)e * 256 * cF + (long)(n0 + sr) * cF + sk16;
  const uint4 zu = make_uint4(0u, 0u, 0u, 0u);
  const int wid = tid >> 6, lane = tid & 63;
  const int wm = (wid >> 1) * 32, wn = (wid & 1) * 32;
  const int fr = lane & 15, fq = lane >> 4;
  float4v zf = {0.f, 0.f, 0.f, 0.f};
  float4v acc[2][2] = {{zf, zf}, {zf, zf}};
  for (int k0 = kbase; k0 < kend; k0 += 64) {
    uint4 a0 = arow ? *reinterpret_cast<const uint4*>(arow + k0)     : zu;
    uint4 a1 = arow ? *reinterpret_cast<const uint4*>(arow + k0 + 8) : zu;
    uint4 b0 = *reinterpret_cast<const uint4*>(brow + k0);
    uint4 b1 = *reinterpret_cast<const uint4*>(brow + k0 + 8);
    *reinterpret_cast<uint4*>(&As[sr * LDK + sk16])     = a0;
    *reinterpret_cast<uint4*>(&As[sr * LDK + sk16 + 8]) = a1;
    *reinterpret_cast<uint4*>(&Bs[sr * LDK + sk16])     = b0;
    *reinterpret_cast<uint4*>(&Bs[sr * LDK + sk16 + 8]) = b1;
    __syncthreads();
#pragma unroll
    for (int ks = 0; ks < 2; ++ks) {
      short8 af[2], bf[2];
#pragma unroll
      for (int mi = 0; mi < 2; ++mi)
        af[mi] = *reinterpret_cast<const short8*>(
            &As[(wm + mi * 16 + fr) * LDK + ks * 32 + fq * 8]);
#pragma unroll
      for (int nj = 0; nj < 2; ++nj)
        bf[nj] = *reinterpret_cast<const short8*>(
            &Bs[(wn + nj * 16 + fr) * LDK + ks * 32 + fq * 8]);
#pragma unroll
      for (int mi = 0; mi < 2; ++mi)
#pragma unroll
        for (int nj = 0; nj < 2; ++nj)
          acc[mi][nj] = MFMA16(af[mi], bf[nj], acc[mi][nj], 0, 0, 0);
    }
    __syncthreads();
  }
  float* dstbase = t3p + (long)ksp * ROWS * 256;
#pragma unroll
  for (int mi = 0; mi < 2; ++mi)
#pragma unroll
    for (int r = 0; r < 4; ++r) {
      int row = m0 + wm + mi * 16 + fq * 4 + r;
      if (row < c) {
        float* dst = dstbase + (long)(o + row) * 256 + n0 + wn;
#pragma unroll
        for (int nj = 0; nj < 2; ++nj)
          dst[nj * 16 + fr] = acc[mi][nj][r];
      }
    }
}

// ---------------------------------------------------------------------------
// y = (sum of 4 t3p partials) @ vd2t^T   [rows x 1024] bf16, plain stores.
// K = 256; partials summed in-register during staging. tile 128x64, BK=32.
// grid = (16, 16, E)
// ---------------------------------------------------------------------------
__global__ __launch_bounds__(256, 2) void k_y(
    const float* __restrict__ t3p, const unsigned short* __restrict__ vd2t,
    unsigned short* __restrict__ y, const int* __restrict__ cnt,
    const int* __restrict__ off)
{
  __shared__ __align__(16) unsigned short As[128 * LDA], Bs[64 * LDA];
  const int e = blockIdx.z, c = cnt[e], o = off[e];
  const int m0 = blockIdx.y * 128;
  if (m0 >= c) return;
  const int n0 = blockIdx.x * 64;
  const int tid = threadIdx.x;
  const int sr = tid >> 2, sk = (tid & 3) * 8;
  const long psz = (long)ROWS * 256;
  const float* ar0 = (m0 + sr < c)      ? t3p + (long)(o + m0 + sr) * 256 + sk      : nullptr;
  const float* ar1 = (m0 + 64 + sr < c) ? t3p + (long)(o + m0 + 64 + sr) * 256 + sk : nullptr;
  const unsigned short* brow = vd2t + (long)e * cH * 256 + (long)(n0 + sr) * 256 + sk;
  const float4 z4 = make_float4(0.f, 0.f, 0.f, 0.f);
  float4 rA0[2], rA1[2];
  uint4 rB;
  auto sum4 = [&](const float* p, int k0) {
    float4 s = *reinterpret_cast<const float4*>(p + k0);
#pragma unroll
    for (int q = 1; q < 4; ++q) {
      float4 t = *reinterpret_cast<const float4*>(p + (long)q * psz + k0);
      s.x += t.x; s.y += t.y; s.z += t.z; s.w += t.w;
    }
    return s;
  };
  auto load_slice = [&](int k0) {
    rA0[0] = ar0 ? sum4(ar0, k0)     : z4;
    rA0[1] = ar0 ? sum4(ar0, k0 + 4) : z4;
    rA1[0] = ar1 ? sum4(ar1, k0)     : z4;
    rA1[1] = ar1 ? sum4(ar1, k0 + 4) : z4;
    rB = *reinterpret_cast<const uint4*>(brow + k0);
  };
  load_slice(0);
  const int wid = tid >> 6, lane = tid & 63;
  const int wm = (wid >> 1) * 64, wn = (wid & 1) * 32;
  const int fr = lane & 15, fq = lane >> 4;
  float4v zf = {0.f, 0.f, 0.f, 0.f};
  float4v acc[4][2];
#pragma unroll
  for (int i = 0; i < 4; ++i) { acc[i][0] = zf; acc[i][1] = zf; }
  for (int k0 = 0; k0 < 256; k0 += 32) {
    store_bf8(&As[sr * LDA + sk], rA0[0], rA0[1]);
    store_bf8(&As[(sr + 64) * LDA + sk], rA1[0], rA1[1]);
    *reinterpret_cast<uint4*>(&Bs[sr * LDA + sk]) = rB;
    if (k0 + 32 < 256) load_slice(k0 + 32);
    __syncthreads();
    short8 af[4], bf[2];
#pragma unroll
    for (int mi = 0; mi < 4; ++mi)
      af[mi] = *reinterpret_cast<const short8*>(&As[(wm + mi * 16 + fr) * LDA + fq * 8]);
#pragma unroll
    for (int nj = 0; nj < 2; ++nj)
      bf[nj] = *reinterpret_cast<const short8*>(&Bs[(wn + nj * 16 + fr) * LDA + fq * 8]);
#pragma unroll
    for (int mi = 0; mi < 4; ++mi)
#pragma unroll
      for (int nj = 0; nj < 2; ++nj)
        acc[mi][nj] = MFMA16(af[mi], bf[nj], acc[mi][nj], 0, 0, 0);
    __syncthreads();
  }
#pragma unroll
  for (int mi = 0; mi < 4; ++mi)
#pragma unroll
    for (int r = 0; r < 4; ++r) {
      int row = m0 + wm + mi * 16 + fq * 4 + r;
      if (row < c) {
#pragma unroll
        for (int nj = 0; nj < 2; ++nj)
          y[(long)(o + row) * cH + n0 + wn + nj * 16 + fr] = f2bf(acc[mi][nj][r]);
      }
    }
}

// ---------------------------------------------------------------------------
// out[t] = w0 * y[rowmap[2t]] + w1 * y[rowmap[2t+1]]   (pure write, no zero)
// ---------------------------------------------------------------------------
__global__ __launch_bounds__(256) void k_combine(
    const unsigned short* __restrict__ y, const float* __restrict__ wt,
    const int* __restrict__ rowmap, float* __restrict__ out)
{
  const int tid = threadIdx.x;
  const int t = blockIdx.x * 2 + (tid >> 7);
  const int h = (tid & 127) * 8;
  const int r0 = rowmap[2 * t], r1 = rowmap[2 * t + 1];
  const float w0 = wt[2 * t], w1 = wt[2 * t + 1];
  union { uint4 v; unsigned short s[8]; } ua, ub;
  ua.v = *reinterpret_cast<const uint4*>(y + (long)r0 * cH + h);
  ub.v = *reinterpret_cast<const uint4*>(y + (long)r1 * cH + h);
  float o[8];
#pragma unroll
  for (int i = 0; i < 8; ++i)
    o[i] = w0 * bf2f(ua.s[i]) + w1 * bf2f(ub.s[i]);
  float* dst = out + (long)t * cH + h;
  *reinterpret_cast<float4*>(dst)     = make_float4(o[0], o[1], o[2], o[3]);
  *reinterpret_cast<float4*>(dst + 4) = make_float4(o[4], o[5], o[6], o[7]);
}

// ---------------------------------------------------------------------------
extern "C" void kernel_launch(void* const* d_in, const int* in_sizes, int n_in,
                              void* d_out, int out_size, void* d_ws, size_t ws_size,
                              hipStream_t stream)
{
  const float* x  = (const float*)d_in[0];
  const float* gw = (const float*)d_in[1];
  const float* Ug = (const float*)d_in[2];
  const float* Cg = (const float*)d_in[3];
  const float* Vg = (const float*)d_in[4];
  const float* Uu = (const float*)d_in[5];
  const float* Cu = (const float*)d_in[6];
  const float* Vu = (const float*)d_in[7];
  const float* Ud = (const float*)d_in[8];
  const float* Cd = (const float*)d_in[9];
  const float* Vd = (const float*)d_in[10];
  float* out = (float*)d_out;

  // workspace layout (~79 MiB peak, with aliasing)
  char* w = (char*)d_ws;
  // [vgT 11.53 | b1t 8.39] phase-1; t3p (16.78, fp32 x4 partials) aliases both
  unsigned short* vgT = (unsigned short*)w;
  float*          t3p = (float*)w;           w += (long)cE * cF * 256 * 2;    // 11.53
  unsigned short* b1t = (unsigned short*)w;  w += (long)cE * 512 * 1024 * 2;  // 8.39
  unsigned short* vd2t = (unsigned short*)w; w += (long)cE * cH * 256 * 2;    // 4.19
  // vuT phase-1; yb (8.39) aliases it in phase 2
  unsigned short* vuT = (unsigned short*)w;
  unsigned short* yb  = (unsigned short*)w;  w += (long)cE * cF * 256 * 2;    // 11.53
  unsigned short* udT = (unsigned short*)w;  w += (long)cE * 256 * cF * 2;    // 11.53
  // VdT used only by fold 3; xb (bf16 x, 4.19 MB) aliases it afterwards
  unsigned short* VdT = (unsigned short*)w;
  unsigned short* xb  = (unsigned short*)w;  w += (long)cE * cH * 256 * 2;    // 4.19
  unsigned short* CgT = (unsigned short*)w;  w += (long)cR * cR * 2;          // 0.13
  unsigned short* CuT = (unsigned short*)w;  w += (long)cR * cR * 2;          // 0.13
  unsigned short* t1  = (unsigned short*)w;  w += (long)ROWS * 512 * 2;       // 4.19
  unsigned short* ab  = (unsigned short*)w;  w += (long)ROWS * cF * 2;        // 23.07
  float* wt   = (float*)w; w += ROWS * 4;
  int* et     = (int*)w; w += ROWS * 4;
  int* rowmap = (int*)w; w += ROWS * 4;
  int* cnt = (int*)w; w += cE * 4;
  int* off = (int*)w; w += cE * 4;

  // 1. gating + lists
  k_gating<<<dim3(cT / 256), dim3(256), 0, stream>>>(x, gw, et, wt);
  k_lists<<<dim3(1), dim3(256), 0, stream>>>(et, rowmap, cnt, off);
  // 2. transposes (fp32 -> bf16)
  k_tconv<<<dim3(cR / 32, cR / 32, 1), dim3(256), 0, stream>>>(Cg, CgT, cR, cR);
  k_tconv<<<dim3(cR / 32, cR / 32, 1), dim3(256), 0, stream>>>(Cu, CuT, cR, cR);
  k_tconv<<<dim3(cH / 32, cR / 32, cE), dim3(256), 0, stream>>>(Vd, VdT, cR, cH);
  k_tconv<<<dim3(cF / 32, cR / 32, cE), dim3(256), 0, stream>>>(Vg, vgT, cR, cF);
  k_tconv<<<dim3(cF / 32, cR / 32, cE), dim3(256), 0, stream>>>(Vu, vuT, cR, cF);
  k_tconv<<<dim3(cR / 32, cF / 32, cE), dim3(256), 0, stream>>>(Ud, udT, cF, cR);
  // 3. MFMA folds (all K=256)
  k_foldm<<<dim3(cH / 64, cR / 128, cE), dim3(256), 0, stream>>>(
      CgT, 0, Ug, (long)cH * cR, b1t, (long)512 * 1024, cH);
  k_foldm<<<dim3(cH / 64, cR / 128, cE), dim3(256), 0, stream>>>(
      CuT, 0, Uu, (long)cH * cR, b1t + (long)256 * 1024, (long)512 * 1024, cH);
  k_foldm<<<dim3(cR / 64, cH / 128, cE), dim3(256), 0, stream>>>(
      VdT, (long)cH * cR, Cd, 0, vd2t, (long)cH * 256, cR);
  // 4. x -> bf16 (overwrites dead VdT)
  k_xconv<<<dim3((cT * cH) / (8 * 256)), dim3(256), 0, stream>>>(x, xb);
  // 5. dense t1 GEMM (async staging) + scatter into compact rows
  k_t1d<<<dim3(32, cT / 128), dim3(256), 0, stream>>>(xb, b1t, t1, et, rowmap);
  // 6. a = silu(t1g @ Vg) * (t1u @ Vu)  (async staging)
  k_act<<<dim3(cF / 64, cT / 128, cE), dim3(256), 0, stream>>>(t1, vgT, vuT, ab, cnt, off);
  // 7. t3p = a @ Ud (split-K=4, plain stores; aliases dead vgT+b1t)
  k_t3<<<dim3(16, cT / 64, cE), dim3(256), 0, stream>>>(ab, udT, t3p, cnt, off);
  // 8. y = (sum t3p) @ Vd2 (plain bf16 stores; aliases dead vuT)
  k_y<<<dim3(cH / 64, cT / 128, cE), dim3(256), 0, stream>>>(t3p, vd2t, yb, cnt, off);
  // 9. out = w0*y[r0] + w1*y[r1]
  k_combine<<<dim3(cT / 2), dim3(256), 0, stream>>>(yb, wt, rowmap, out);
}

// Round 7
// 342.531 us; speedup vs baseline: 1.6375x; 1.1276x over previous
//
#include <hip/hip_runtime.h>
#include <math.h>

constexpr int cE = 8;
constexpr int cH = 1024;
constexpr int cF = 2816;
constexpr int cR = 256;
constexpr int cT = 2048;
constexpr int ROWS = cT * 2;   // total routed (token, expert) rows = T*K
constexpr int LDA = 40;        // padded LDS row stride (BK=32 reg-staged kernels)
constexpr int LDK = 72;        // padded LDS row stride (BK=64 reg-staged kernels)

using short8  = __attribute__((ext_vector_type(8))) short;
using float4v = __attribute__((ext_vector_type(4))) float;
#define MFMA16 __builtin_amdgcn_mfma_f32_16x16x32_bf16

__device__ __forceinline__ unsigned short f2bf(float f) {
  union { float f; unsigned u; } v; v.f = f;
  unsigned r = v.u + 0x7fffu + ((v.u >> 16) & 1u);   // RNE
  return (unsigned short)(r >> 16);
}
__device__ __forceinline__ float bf2f(unsigned short s) {
  union { unsigned u; float f; } v; v.u = (unsigned)s << 16; return v.f;
}

// pack 8 fp32 -> 8 bf16, single 16B store
__device__ __forceinline__ void store_bf8(unsigned short* dst, float4 a, float4 b) {
  union { unsigned short u[8]; uint4 v; } t;
  t.u[0] = f2bf(a.x); t.u[1] = f2bf(a.y); t.u[2] = f2bf(a.z); t.u[3] = f2bf(a.w);
  t.u[4] = f2bf(b.x); t.u[5] = f2bf(b.y); t.u[6] = f2bf(b.z); t.u[7] = f2bf(b.w);
  *reinterpret_cast<uint4*>(dst) = t.v;
}

// async global->LDS, 16 B per lane. LDS dest = wave-uniform base + lane*16.
__device__ __forceinline__ void gld16(const unsigned short* g, unsigned short* l) {
  __builtin_amdgcn_global_load_lds(
      (const __attribute__((address_space(1))) void*)g,
      (__attribute__((address_space(3))) void*)l, 16, 0, 0);
}

// ---------------------------------------------------------------------------
// gating (wave-per-token) + x->bf16 conversion fused.
// grid = (cT/4), 256 threads = 4 waves; each wave owns one token.
// Lane j holds x[t][j*16 .. j*16+15]; writes bf16 copy; computes 8 logit
// partials; 64-lane butterfly reduce; lane 0 does top-2 + weights.
// ---------------------------------------------------------------------------
__global__ __launch_bounds__(256) void k_gating(
    const float* __restrict__ x, const float* __restrict__ gw,
    unsigned short* __restrict__ xb, int* __restrict__ et,
    float* __restrict__ wt)
{
  const int tid = threadIdx.x;
  const int wid = tid >> 6, lane = tid & 63;
  const int t = blockIdx.x * 4 + wid;
  const float* xr = x + (long)t * cH + lane * 16;
  float4 v0 = *reinterpret_cast<const float4*>(xr);
  float4 v1 = *reinterpret_cast<const float4*>(xr + 4);
  float4 v2 = *reinterpret_cast<const float4*>(xr + 8);
  float4 v3 = *reinterpret_cast<const float4*>(xr + 12);
  store_bf8(xb + (long)t * cH + lane * 16, v0, v1);
  store_bf8(xb + (long)t * cH + lane * 16 + 8, v2, v3);
  float xv[16];
  *reinterpret_cast<float4*>(&xv[0])  = v0;
  *reinterpret_cast<float4*>(&xv[4])  = v1;
  *reinterpret_cast<float4*>(&xv[8])  = v2;
  *reinterpret_cast<float4*>(&xv[12]) = v3;
  const float* g = gw + (long)lane * 16 * cE;
  float l[cE];
#pragma unroll
  for (int e = 0; e < cE; ++e) l[e] = 0.f;
#pragma unroll
  for (int i = 0; i < 16; ++i) {
    float4 ga = *reinterpret_cast<const float4*>(g + i * cE);
    float4 gb = *reinterpret_cast<const float4*>(g + i * cE + 4);
    float xi = xv[i];
    l[0] += xi * ga.x; l[1] += xi * ga.y; l[2] += xi * ga.z; l[3] += xi * ga.w;
    l[4] += xi * gb.x; l[5] += xi * gb.y; l[6] += xi * gb.z; l[7] += xi * gb.w;
  }
#pragma unroll
  for (int m = 1; m < 64; m <<= 1)
#pragma unroll
    for (int e = 0; e < cE; ++e)
      l[e] += __shfl_xor(l[e], m, 64);
  if (lane == 0) {
    int i0 = 0; float m0 = l[0];
#pragma unroll
    for (int e = 1; e < cE; ++e) if (l[e] > m0) { m0 = l[e]; i0 = e; }
    int i1 = -1; float m1 = -1e30f;
#pragma unroll
    for (int e = 0; e < cE; ++e) if (e != i0 && l[e] > m1) { m1 = l[e]; i1 = e; }
    float w0 = 1.f / (1.f + expf(m1 - m0));
    et[t * 2 + 0] = i0;  et[t * 2 + 1] = i1;
    wt[t * 2 + 0] = w0;  wt[t * 2 + 1] = 1.f - w0;
  }
}

// ---------------------------------------------------------------------------
// build compact per-expert token lists + inverse map (single block)
// ---------------------------------------------------------------------------
__global__ __launch_bounds__(256) void k_lists(
    const int* __restrict__ et, int* __restrict__ rowmap,
    int* __restrict__ cnt, int* __restrict__ off)
{
  __shared__ int c[cE], p[cE], o[cE];
  const int tid = threadIdx.x;
  if (tid < cE) { c[tid] = 0; p[tid] = 0; }
  __syncthreads();
  for (int i = tid; i < ROWS; i += 256) atomicAdd(&c[et[i]], 1);
  __syncthreads();
  if (tid == 0) {
    int s = 0;
    for (int e = 0; e < cE; ++e) { o[e] = s; s += c[e]; }
  }
  __syncthreads();
  for (int i = tid; i < ROWS; i += 256) {
    int e = et[i];
    int slot = atomicAdd(&p[e], 1);
    rowmap[i] = o[e] + slot;
  }
  if (tid < cE) { cnt[tid] = c[tid]; off[tid] = o[tid]; }
}

// ---------------------------------------------------------------------------
// transpose + fp32->bf16: in [P][Q] per batch -> out [Q][P] per batch
// ---------------------------------------------------------------------------
__global__ __launch_bounds__(256) void k_tconv(
    const float* __restrict__ in, unsigned short* __restrict__ out, int P, int Q)
{
  __shared__ float tile[32][33];
  const long es = (long)P * Q;
  const int e = blockIdx.z;
  in += e * es; out += e * es;
  const int c0 = blockIdx.x * 32, r0 = blockIdx.y * 32;
  const int tid = threadIdx.x;
  const int r = tid >> 3, c4 = (tid & 7) * 4;
  float4 v = *reinterpret_cast<const float4*>(in + (long)(r0 + r) * Q + c0 + c4);
  tile[r][c4 + 0] = v.x; tile[r][c4 + 1] = v.y;
  tile[r][c4 + 2] = v.z; tile[r][c4 + 3] = v.w;
  __syncthreads();
  const int cc = tid >> 3, rr4 = (tid & 7) * 4;
  ushort4 o;
  o.x = f2bf(tile[rr4 + 0][cc]);
  o.y = f2bf(tile[rr4 + 1][cc]);
  o.z = f2bf(tile[rr4 + 2][cc]);
  o.w = f2bf(tile[rr4 + 3][cc]);
  *reinterpret_cast<ushort4*>(out + (long)(c0 + cc) * P + r0 + rr4) = o;
}

// ---------------------------------------------------------------------------
// MFMA fold: D[m][n] = sum_k A[m][k] * B[n][k],  K = 256 fixed.
// tile 128x64, BK=32, register prefetch. grid = (N/64, M/128, E)
// ---------------------------------------------------------------------------
__global__ __launch_bounds__(256, 2) void k_foldm(
    const unsigned short* __restrict__ A, long sA,
    const float* __restrict__ B, long sB,
    unsigned short* __restrict__ D, long sD, int ldd)
{
  __shared__ __align__(16) unsigned short As[128 * LDA], Bs[64 * LDA];
  const int e = blockIdx.z;
  A += e * sA; B += e * sB; D += e * sD;
  const int m0 = blockIdx.y * 128, n0 = blockIdx.x * 64;
  const int tid = threadIdx.x;
  const int sr = tid >> 2, sk = (tid & 3) * 8;
  const unsigned short* a0 = A + (long)(m0 + sr) * 256 + sk;
  const unsigned short* a1 = a0 + (long)64 * 256;
  const float* br = B + (long)(n0 + sr) * 256 + sk;
  uint4 rA0, rA1; float4 rB0, rB1;
  auto load_slice = [&](int k0) {
    rA0 = *reinterpret_cast<const uint4*>(a0 + k0);
    rA1 = *reinterpret_cast<const uint4*>(a1 + k0);
    rB0 = *reinterpret_cast<const float4*>(br + k0);
    rB1 = *reinterpret_cast<const float4*>(br + k0 + 4);
  };
  load_slice(0);
  const int wid = tid >> 6, lane = tid & 63;
  const int wm = (wid >> 1) * 64, wn = (wid & 1) * 32;
  const int fr = lane & 15, fq = lane >> 4;
  float4v zf = {0.f, 0.f, 0.f, 0.f};
  float4v acc[4][2];
#pragma unroll
  for (int i = 0; i < 4; ++i) { acc[i][0] = zf; acc[i][1] = zf; }
  for (int k0 = 0; k0 < 256; k0 += 32) {
    *reinterpret_cast<uint4*>(&As[sr * LDA + sk]) = rA0;
    *reinterpret_cast<uint4*>(&As[(sr + 64) * LDA + sk]) = rA1;
    store_bf8(&Bs[sr * LDA + sk], rB0, rB1);
    if (k0 + 32 < 256) load_slice(k0 + 32);
    __syncthreads();
    short8 af[4], bf[2];
#pragma unroll
    for (int mi = 0; mi < 4; ++mi)
      af[mi] = *reinterpret_cast<const short8*>(&As[(wm + mi * 16 + fr) * LDA + fq * 8]);
#pragma unroll
    for (int nj = 0; nj < 2; ++nj)
      bf[nj] = *reinterpret_cast<const short8*>(&Bs[(wn + nj * 16 + fr) * LDA + fq * 8]);
#pragma unroll
    for (int mi = 0; mi < 4; ++mi)
#pragma unroll
      for (int nj = 0; nj < 2; ++nj)
        acc[mi][nj] = MFMA16(af[mi], bf[nj], acc[mi][nj], 0, 0, 0);
    __syncthreads();
  }
#pragma unroll
  for (int mi = 0; mi < 4; ++mi)
#pragma unroll
    for (int r = 0; r < 4; ++r) {
      int m = m0 + wm + mi * 16 + fq * 4 + r;
#pragma unroll
      for (int nj = 0; nj < 2; ++nj)
        D[(long)m * ldd + n0 + wn + nj * 16 + fr] = f2bf(acc[mi][nj][r]);
    }
}

// ---------------------------------------------------------------------------
// DENSE t1 GEMM + scatter epilogue — m97-style async staging.
// C[2048][4096] = xb @ b1t^T (both bf16, K-contiguous); each 128x128 tile
// writes only rows routed to this tile's expert into compact t1[row][512].
// BK=64, unpadded LDS [128][64], global_load_lds width 16. grid = (32, 16)
// ---------------------------------------------------------------------------
__global__ __launch_bounds__(256, 2) void k_t1d(
    const unsigned short* __restrict__ xb, const unsigned short* __restrict__ b1t,
    unsigned short* __restrict__ t1, const int* __restrict__ et,
    const int* __restrict__ rowmap)
{
  __shared__ __align__(16) unsigned short As[128 * 64];
  __shared__ __align__(16) unsigned short Bs[128 * 64];
  const int tid = threadIdx.x;
  const int wid = tid >> 6, lane = tid & 63;
  const int m0 = blockIdx.y * 128;
  const int nb = blockIdx.x;                 // 0..31
  const int srow = wid * 32 + (lane >> 3);
  const int scol = (lane & 7) * 8;
  const unsigned short* gA = xb + (long)(m0 + srow) * cH + scol;
  const unsigned short* gB = b1t + (long)(nb * 128 + srow) * cH + scol;
  unsigned short* lA = As + wid * 32 * 64;   // wave-uniform
  unsigned short* lB = Bs + wid * 32 * 64;
  const int wm = (wid >> 1) * 64, wn = (wid & 1) * 64;
  const int fr = lane & 15, fq = lane >> 4;
  float4v zf = {0.f, 0.f, 0.f, 0.f};
  float4v acc[4][4];
#pragma unroll
  for (int i = 0; i < 4; ++i)
#pragma unroll
    for (int j = 0; j < 4; ++j) acc[i][j] = zf;
  for (int k0 = 0; k0 < cH; k0 += 64) {
#pragma unroll
    for (int j = 0; j < 4; ++j) {
      gld16(gA + k0 + (long)j * 8 * cH, lA + j * 8 * 64);
      gld16(gB + k0 + (long)j * 8 * cH, lB + j * 8 * 64);
    }
    __syncthreads();
#pragma unroll
    for (int ks = 0; ks < 2; ++ks) {
      short8 af[4], bf[4];
#pragma unroll
      for (int mi = 0; mi < 4; ++mi)
        af[mi] = *reinterpret_cast<const short8*>(
            &As[(wm + mi * 16 + fr) * 64 + ks * 32 + fq * 8]);
#pragma unroll
      for (int nj = 0; nj < 4; ++nj)
        bf[nj] = *reinterpret_cast<const short8*>(
            &Bs[(wn + nj * 16 + fr) * 64 + ks * 32 + fq * 8]);
#pragma unroll
      for (int mi = 0; mi < 4; ++mi)
#pragma unroll
        for (int nj = 0; nj < 4; ++nj)
          acc[mi][nj] = MFMA16(af[mi], bf[nj], acc[mi][nj], 0, 0, 0);
    }
    __syncthreads();
  }
  const int e_t = nb >> 2;
  const int colbase = (nb & 3) * 128 + wn;
#pragma unroll
  for (int mi = 0; mi < 4; ++mi)
#pragma unroll
    for (int r = 0; r < 4; ++r) {
      int t = m0 + wm + mi * 16 + fq * 4 + r;
      int crow = -1;
      if (et[2 * t] == e_t) crow = rowmap[2 * t];
      else if (et[2 * t + 1] == e_t) crow = rowmap[2 * t + 1];
      if (crow >= 0) {
#pragma unroll
        for (int nj = 0; nj < 4; ++nj)
          t1[(long)crow * 512 + colbase + nj * 16 + fr] = f2bf(acc[mi][nj][r]);
      }
    }
}

// ---------------------------------------------------------------------------
// dual GEMM: a = silu(t1g @ vgT^T) * (t1u @ vuT^T)  [rows x F], K=256
// async staging (global_load_lds), unpadded LDS, BK=32. grid = (44, 16, E)
// ---------------------------------------------------------------------------
__global__ __launch_bounds__(256, 2) void k_act(
    const unsigned short* __restrict__ t1,
    const unsigned short* __restrict__ vgT, const unsigned short* __restrict__ vuT,
    unsigned short* __restrict__ a, const int* __restrict__ cnt,
    const int* __restrict__ off)
{
  __shared__ __align__(16) unsigned short Ag[128 * 32], Au[128 * 32];
  __shared__ __align__(16) unsigned short Bg[64 * 32],  Bu[64 * 32];
  const int e = blockIdx.z, c = cnt[e], o = off[e];
  const int m0 = blockIdx.y * 128;
  if (m0 >= c) return;
  const int n0 = blockIdx.x * 64;
  const int tid = threadIdx.x;
  const int wid = tid >> 6, lane = tid & 63;
  const int sr16 = lane >> 2, sc = (lane & 3) * 8;
  const unsigned short* gAg = t1 + (long)(o + m0 + wid * 32 + sr16) * 512 + sc;
  const unsigned short* gAu = gAg + 256;
  const unsigned short* gBg = vgT + (long)e * cF * 256 + (long)(n0 + wid * 16 + sr16) * 256 + sc;
  const unsigned short* gBu = vuT + (long)e * cF * 256 + (long)(n0 + wid * 16 + sr16) * 256 + sc;
  unsigned short* lAg = Ag + wid * 32 * 32;
  unsigned short* lAu = Au + wid * 32 * 32;
  unsigned short* lBg = Bg + wid * 16 * 32;
  unsigned short* lBu = Bu + wid * 16 * 32;
  const int wm = (wid >> 1) * 64, wn = (wid & 1) * 32;
  const int fr = lane & 15, fq = lane >> 4;
  float4v zf = {0.f, 0.f, 0.f, 0.f};
  float4v accg[4][2], accu[4][2];
#pragma unroll
  for (int i = 0; i < 4; ++i) { accg[i][0] = zf; accg[i][1] = zf; accu[i][0] = zf; accu[i][1] = zf; }
  for (int k0 = 0; k0 < 256; k0 += 32) {
#pragma unroll
    for (int j = 0; j < 2; ++j) {
      gld16(gAg + (long)j * 16 * 512 + k0, lAg + j * 16 * 32);
      gld16(gAu + (long)j * 16 * 512 + k0, lAu + j * 16 * 32);
    }
    gld16(gBg + k0, lBg);
    gld16(gBu + k0, lBu);
    __syncthreads();
    short8 ag[4], au[4], bg[2], bu[2];
#pragma unroll
    for (int mi = 0; mi < 4; ++mi) {
      ag[mi] = *reinterpret_cast<const short8*>(&Ag[(wm + mi * 16 + fr) * 32 + fq * 8]);
      au[mi] = *reinterpret_cast<const short8*>(&Au[(wm + mi * 16 + fr) * 32 + fq * 8]);
    }
#pragma unroll
    for (int nj = 0; nj < 2; ++nj) {
      bg[nj] = *reinterpret_cast<const short8*>(&Bg[(wn + nj * 16 + fr) * 32 + fq * 8]);
      bu[nj] = *reinterpret_cast<const short8*>(&Bu[(wn + nj * 16 + fr) * 32 + fq * 8]);
    }
#pragma unroll
    for (int mi = 0; mi < 4; ++mi)
#pragma unroll
      for (int nj = 0; nj < 2; ++nj) {
        accg[mi][nj] = MFMA16(ag[mi], bg[nj], accg[mi][nj], 0, 0, 0);
        accu[mi][nj] = MFMA16(au[mi], bu[nj], accu[mi][nj], 0, 0, 0);
      }
    __syncthreads();
  }
#pragma unroll
  for (int mi = 0; mi < 4; ++mi)
#pragma unroll
    for (int r = 0; r < 4; ++r) {
      int row = m0 + wm + mi * 16 + fq * 4 + r;
      if (row < c) {
#pragma unroll
        for (int nj = 0; nj < 2; ++nj) {
          float g = accg[mi][nj][r];
          float u = accu[mi][nj][r];
          float s = g / (1.f + expf(-g)) * u;
          a[(long)(o + row) * cF + n0 + wn + nj * 16 + fr] = f2bf(s);
        }
      }
    }
}

// ---------------------------------------------------------------------------
// t3p[ks] = a @ udT^T (split-K=4, plain fp32 stores).  [4][ROWS][256].
// inline staging, NO min-wave cap. tile 64x64, BK=64, 11 iters.
// grid = (16, 32, E): x = n(0..3) | ksp(0..3)<<2
// ---------------------------------------------------------------------------
__global__ __launch_bounds__(256) void k_t3(
    const unsigned short* __restrict__ a, const unsigned short* __restrict__ udT,
    float* __restrict__ t3p, const int* __restrict__ cnt,
    const int* __restrict__ off)
{
  __shared__ __align__(16) unsigned short As[64 * LDK], Bs[64 * LDK];
  const int e = blockIdx.z, c = cnt[e], o = off[e];
  const int m0 = blockIdx.y * 64;
  if (m0 >= c) return;
  const int n0 = (blockIdx.x & 3) * 64;
  const int ksp = blockIdx.x >> 2;                 // 0..3
  const int kbase = ksp * 704, kend = kbase + 704;
  const int tid = threadIdx.x;
  const int sr = tid >> 2, sk16 = (tid & 3) * 16;
  const unsigned short* arow = (m0 + sr < c)
      ? a + (long)(o + m0 + sr) * cF + sk16 : nullptr;
  const unsigned short* brow = udT + (long)e * 256 * cF + (long)(n0 + sr) * cF + sk16;
  const uint4 zu = make_uint4(0u, 0u, 0u, 0u);
  const int wid = tid >> 6, lane = tid & 63;
  const int wm = (wid >> 1) * 32, wn = (wid & 1) * 32;
  const int fr = lane & 15, fq = lane >> 4;
  float4v zf = {0.f, 0.f, 0.f, 0.f};
  float4v acc[2][2] = {{zf, zf}, {zf, zf}};
  for (int k0 = kbase; k0 < kend; k0 += 64) {
    uint4 a0 = arow ? *reinterpret_cast<const uint4*>(arow + k0)     : zu;
    uint4 a1 = arow ? *reinterpret_cast<const uint4*>(arow + k0 + 8) : zu;
    uint4 b0 = *reinterpret_cast<const uint4*>(brow + k0);
    uint4 b1 = *reinterpret_cast<const uint4*>(brow + k0 + 8);
    *reinterpret_cast<uint4*>(&As[sr * LDK + sk16])     = a0;
    *reinterpret_cast<uint4*>(&As[sr * LDK + sk16 + 8]) = a1;
    *reinterpret_cast<uint4*>(&Bs[sr * LDK + sk16])     = b0;
    *reinterpret_cast<uint4*>(&Bs[sr * LDK + sk16 + 8]) = b1;
    __syncthreads();
#pragma unroll
    for (int ks = 0; ks < 2; ++ks) {
      short8 af[2], bf[2];
#pragma unroll
      for (int mi = 0; mi < 2; ++mi)
        af[mi] = *reinterpret_cast<const short8*>(
            &As[(wm + mi * 16 + fr) * LDK + ks * 32 + fq * 8]);
#pragma unroll
      for (int nj = 0; nj < 2; ++nj)
        bf[nj] = *reinterpret_cast<const short8*>(
            &Bs[(wn + nj * 16 + fr) * LDK + ks * 32 + fq * 8]);
#pragma unroll
      for (int mi = 0; mi < 2; ++mi)
#pragma unroll
        for (int nj = 0; nj < 2; ++nj)
          acc[mi][nj] = MFMA16(af[mi], bf[nj], acc[mi][nj], 0, 0, 0);
    }
    __syncthreads();
  }
  float* dstbase = t3p + (long)ksp * ROWS * 256;
#pragma unroll
  for (int mi = 0; mi < 2; ++mi)
#pragma unroll
    for (int r = 0; r < 4; ++r) {
      int row = m0 + wm + mi * 16 + fq * 4 + r;
      if (row < c) {
        float* dst = dstbase + (long)(o + row) * 256 + n0 + wn;
#pragma unroll
        for (int nj = 0; nj < 2; ++nj)
          dst[nj * 16 + fr] = acc[mi][nj][r];
      }
    }
}

// ---------------------------------------------------------------------------
// y = (sum of 4 t3p partials) @ vd2t^T   [rows x 1024] bf16, plain stores.
// K = 256; partials summed in-register during staging. tile 128x64, BK=32.
// grid = (16, 16, E)
// ---------------------------------------------------------------------------
__global__ __launch_bounds__(256, 2) void k_y(
    const float* __restrict__ t3p, const unsigned short* __restrict__ vd2t,
    unsigned short* __restrict__ y, const int* __restrict__ cnt,
    const int* __restrict__ off)
{
  __shared__ __align__(16) unsigned short As[128 * LDA], Bs[64 * LDA];
  const int e = blockIdx.z, c = cnt[e], o = off[e];
  const int m0 = blockIdx.y * 128;
  if (m0 >= c) return;
  const int n0 = blockIdx.x * 64;
  const int tid = threadIdx.x;
  const int sr = tid >> 2, sk = (tid & 3) * 8;
  const long psz = (long)ROWS * 256;
  const float* ar0 = (m0 + sr < c)      ? t3p + (long)(o + m0 + sr) * 256 + sk      : nullptr;
  const float* ar1 = (m0 + 64 + sr < c) ? t3p + (long)(o + m0 + 64 + sr) * 256 + sk : nullptr;
  const unsigned short* brow = vd2t + (long)e * cH * 256 + (long)(n0 + sr) * 256 + sk;
  const float4 z4 = make_float4(0.f, 0.f, 0.f, 0.f);
  float4 rA0[2], rA1[2];
  uint4 rB;
  auto sum4 = [&](const float* p, int k0) {
    float4 s = *reinterpret_cast<const float4*>(p + k0);
#pragma unroll
    for (int q = 1; q < 4; ++q) {
      float4 t = *reinterpret_cast<const float4*>(p + (long)q * psz + k0);
      s.x += t.x; s.y += t.y; s.z += t.z; s.w += t.w;
    }
    return s;
  };
  auto load_slice = [&](int k0) {
    rA0[0] = ar0 ? sum4(ar0, k0)     : z4;
    rA0[1] = ar0 ? sum4(ar0, k0 + 4) : z4;
    rA1[0] = ar1 ? sum4(ar1, k0)     : z4;
    rA1[1] = ar1 ? sum4(ar1, k0 + 4) : z4;
    rB = *reinterpret_cast<const uint4*>(brow + k0);
  };
  load_slice(0);
  const int wid = tid >> 6, lane = tid & 63;
  const int wm = (wid >> 1) * 64, wn = (wid & 1) * 32;
  const int fr = lane & 15, fq = lane >> 4;
  float4v zf = {0.f, 0.f, 0.f, 0.f};
  float4v acc[4][2];
#pragma unroll
  for (int i = 0; i < 4; ++i) { acc[i][0] = zf; acc[i][1] = zf; }
  for (int k0 = 0; k0 < 256; k0 += 32) {
    store_bf8(&As[sr * LDA + sk], rA0[0], rA0[1]);
    store_bf8(&As[(sr + 64) * LDA + sk], rA1[0], rA1[1]);
    *reinterpret_cast<uint4*>(&Bs[sr * LDA + sk]) = rB;
    if (k0 + 32 < 256) load_slice(k0 + 32);
    __syncthreads();
    short8 af[4], bf[2];
#pragma unroll
    for (int mi = 0; mi < 4; ++mi)
      af[mi] = *reinterpret_cast<const short8*>(&As[(wm + mi * 16 + fr) * LDA + fq * 8]);
#pragma unroll
    for (int nj = 0; nj < 2; ++nj)
      bf[nj] = *reinterpret_cast<const short8*>(&Bs[(wn + nj * 16 + fr) * LDA + fq * 8]);
#pragma unroll
    for (int mi = 0; mi < 4; ++mi)
#pragma unroll
      for (int nj = 0; nj < 2; ++nj)
        acc[mi][nj] = MFMA16(af[mi], bf[nj], acc[mi][nj], 0, 0, 0);
    __syncthreads();
  }
#pragma unroll
  for (int mi = 0; mi < 4; ++mi)
#pragma unroll
    for (int r = 0; r < 4; ++r) {
      int row = m0 + wm + mi * 16 + fq * 4 + r;
      if (row < c) {
#pragma unroll
        for (int nj = 0; nj < 2; ++nj)
          y[(long)(o + row) * cH + n0 + wn + nj * 16 + fr] = f2bf(acc[mi][nj][r]);
      }
    }
}

// ---------------------------------------------------------------------------
// out[t] = w0 * y[rowmap[2t]] + w1 * y[rowmap[2t+1]]   (pure write, no zero)
// ---------------------------------------------------------------------------
__global__ __launch_bounds__(256) void k_combine(
    const unsigned short* __restrict__ y, const float* __restrict__ wt,
    const int* __restrict__ rowmap, float* __restrict__ out)
{
  const int tid = threadIdx.x;
  const int t = blockIdx.x * 2 + (tid >> 7);
  const int h = (tid & 127) * 8;
  const int r0 = rowmap[2 * t], r1 = rowmap[2 * t + 1];
  const float w0 = wt[2 * t], w1 = wt[2 * t + 1];
  union { uint4 v; unsigned short s[8]; } ua, ub;
  ua.v = *reinterpret_cast<const uint4*>(y + (long)r0 * cH + h);
  ub.v = *reinterpret_cast<const uint4*>(y + (long)r1 * cH + h);
  float o[8];
#pragma unroll
  for (int i = 0; i < 8; ++i)
    o[i] = w0 * bf2f(ua.s[i]) + w1 * bf2f(ub.s[i]);
  float* dst = out + (long)t * cH + h;
  *reinterpret_cast<float4*>(dst)     = make_float4(o[0], o[1], o[2], o[3]);
  *reinterpret_cast<float4*>(dst + 4) = make_float4(o[4], o[5], o[6], o[7]);
}

// ---------------------------------------------------------------------------
extern "C" void kernel_launch(void* const* d_in, const int* in_sizes, int n_in,
                              void* d_out, int out_size, void* d_ws, size_t ws_size,
                              hipStream_t stream)
{
  const float* x  = (const float*)d_in[0];
  const float* gw = (const float*)d_in[1];
  const float* Ug = (const float*)d_in[2];
  const float* Cg = (const float*)d_in[3];
  const float* Vg = (const float*)d_in[4];
  const float* Uu = (const float*)d_in[5];
  const float* Cu = (const float*)d_in[6];
  const float* Vu = (const float*)d_in[7];
  const float* Ud = (const float*)d_in[8];
  const float* Cd = (const float*)d_in[9];
  const float* Vd = (const float*)d_in[10];
  float* out = (float*)d_out;

  // workspace layout (~79 MiB peak, with aliasing)
  char* w = (char*)d_ws;
  // [vgT 11.53 | b1t 8.39] phase-1; t3p (16.78, fp32 x4 partials) aliases both
  unsigned short* vgT = (unsigned short*)w;
  float*          t3p = (float*)w;           w += (long)cE * cF * 256 * 2;    // 11.53
  unsigned short* b1t = (unsigned short*)w;  w += (long)cE * 512 * 1024 * 2;  // 8.39
  unsigned short* vd2t = (unsigned short*)w; w += (long)cE * cH * 256 * 2;    // 4.19
  // vuT phase-1; yb (8.39) aliases it in phase 2
  unsigned short* vuT = (unsigned short*)w;
  unsigned short* yb  = (unsigned short*)w;  w += (long)cE * cF * 256 * 2;    // 11.53
  unsigned short* udT = (unsigned short*)w;  w += (long)cE * 256 * cF * 2;    // 11.53
  // VdT consumed by fold 3; xb (bf16 x, 4.19 MB) aliases it afterwards
  unsigned short* VdT = (unsigned short*)w;
  unsigned short* xb  = (unsigned short*)w;  w += (long)cE * cH * 256 * 2;    // 4.19
  unsigned short* CgT = (unsigned short*)w;  w += (long)cR * cR * 2;          // 0.13
  unsigned short* CuT = (unsigned short*)w;  w += (long)cR * cR * 2;          // 0.13
  unsigned short* t1  = (unsigned short*)w;  w += (long)ROWS * 512 * 2;       // 4.19
  unsigned short* ab  = (unsigned short*)w;  w += (long)ROWS * cF * 2;        // 23.07
  float* wt   = (float*)w; w += ROWS * 4;
  int* et     = (int*)w; w += ROWS * 4;
  int* rowmap = (int*)w; w += ROWS * 4;
  int* cnt = (int*)w; w += cE * 4;
  int* off = (int*)w; w += cE * 4;

  // 1. transposes (fp32 -> bf16)
  k_tconv<<<dim3(cR / 32, cR / 32, 1), dim3(256), 0, stream>>>(Cg, CgT, cR, cR);
  k_tconv<<<dim3(cR / 32, cR / 32, 1), dim3(256), 0, stream>>>(Cu, CuT, cR, cR);
  k_tconv<<<dim3(cH / 32, cR / 32, cE), dim3(256), 0, stream>>>(Vd, VdT, cR, cH);
  k_tconv<<<dim3(cF / 32, cR / 32, cE), dim3(256), 0, stream>>>(Vg, vgT, cR, cF);
  k_tconv<<<dim3(cF / 32, cR / 32, cE), dim3(256), 0, stream>>>(Vu, vuT, cR, cF);
  k_tconv<<<dim3(cR / 32, cF / 32, cE), dim3(256), 0, stream>>>(Ud, udT, cF, cR);
  // 2. MFMA folds (all K=256)
  k_foldm<<<dim3(cH / 64, cR / 128, cE), dim3(256), 0, stream>>>(
      CgT, 0, Ug, (long)cH * cR, b1t, (long)512 * 1024, cH);
  k_foldm<<<dim3(cH / 64, cR / 128, cE), dim3(256), 0, stream>>>(
      CuT, 0, Uu, (long)cH * cR, b1t + (long)256 * 1024, (long)512 * 1024, cH);
  k_foldm<<<dim3(cR / 64, cH / 128, cE), dim3(256), 0, stream>>>(
      VdT, (long)cH * cR, Cd, 0, vd2t, (long)cH * 256, cR);
  // 3. gating + x->bf16 (xb overwrites dead VdT) + lists
  k_gating<<<dim3(cT / 4), dim3(256), 0, stream>>>(x, gw, xb, et, wt);
  k_lists<<<dim3(1), dim3(256), 0, stream>>>(et, rowmap, cnt, off);
  // 4. dense t1 GEMM (async staging) + scatter into compact rows
  k_t1d<<<dim3(32, cT / 128), dim3(256), 0, stream>>>(xb, b1t, t1, et, rowmap);
  // 5. a = silu(t1g @ Vg) * (t1u @ Vu)  (async staging)
  k_act<<<dim3(cF / 64, cT / 128, cE), dim3(256), 0, stream>>>(t1, vgT, vuT, ab, cnt, off);
  // 6. t3p = a @ Ud (split-K=4, plain stores; aliases dead vgT+b1t)
  k_t3<<<dim3(16, cT / 64, cE), dim3(256), 0, stream>>>(ab, udT, t3p, cnt, off);
  // 7. y = (sum t3p) @ Vd2 (plain bf16 stores; aliases dead vuT)
  k_y<<<dim3(cH / 64, cT / 128, cE), dim3(256), 0, stream>>>(t3p, vd2t, yb, cnt, off);
  // 8. out = w0*y[r0] + w1*y[r1]
  k_combine<<<dim3(cT / 2), dim3(256), 0, stream>>>(yb, wt, rowmap, out);
}

// Round 8
// 310.860 us; speedup vs baseline: 1.8043x; 1.1019x over previous
//
#include <hip/hip_runtime.h>
#include <math.h>

constexpr int cE = 8;
constexpr int cH = 1024;
constexpr int cF = 2816;
constexpr int cR = 256;
constexpr int cT = 2048;
constexpr int ROWS = cT * 2;   // total routed (token, expert) rows = T*K
constexpr int LDA = 40;        // padded LDS row stride (BK=32 reg-staged kernels)

using short8  = __attribute__((ext_vector_type(8))) short;
using float4v = __attribute__((ext_vector_type(4))) float;
#define MFMA16 __builtin_amdgcn_mfma_f32_16x16x32_bf16

__device__ __forceinline__ unsigned short f2bf(float f) {
  union { float f; unsigned u; } v; v.f = f;
  unsigned r = v.u + 0x7fffu + ((v.u >> 16) & 1u);   // RNE
  return (unsigned short)(r >> 16);
}
__device__ __forceinline__ float bf2f(unsigned short s) {
  union { unsigned u; float f; } v; v.u = (unsigned)s << 16; return v.f;
}

// pack 8 fp32 -> 8 bf16, single 16B store
__device__ __forceinline__ void store_bf8(unsigned short* dst, float4 a, float4 b) {
  union { unsigned short u[8]; uint4 v; } t;
  t.u[0] = f2bf(a.x); t.u[1] = f2bf(a.y); t.u[2] = f2bf(a.z); t.u[3] = f2bf(a.w);
  t.u[4] = f2bf(b.x); t.u[5] = f2bf(b.y); t.u[6] = f2bf(b.z); t.u[7] = f2bf(b.w);
  *reinterpret_cast<uint4*>(dst) = t.v;
}

// async global->LDS, 16 B per lane. LDS dest = wave-uniform base + lane*16.
__device__ __forceinline__ void gld16(const unsigned short* g, unsigned short* l) {
  __builtin_amdgcn_global_load_lds(
      (const __attribute__((address_space(1))) void*)g,
      (__attribute__((address_space(3))) void*)l, 16, 0, 0);
}

// ---------------------------------------------------------------------------
// gating (wave-per-token) + x->bf16 conversion fused.
// ---------------------------------------------------------------------------
__global__ __launch_bounds__(256) void k_gating(
    const float* __restrict__ x, const float* __restrict__ gw,
    unsigned short* __restrict__ xb, int* __restrict__ et,
    float* __restrict__ wt)
{
  const int tid = threadIdx.x;
  const int wid = tid >> 6, lane = tid & 63;
  const int t = blockIdx.x * 4 + wid;
  const float* xr = x + (long)t * cH + lane * 16;
  float4 v0 = *reinterpret_cast<const float4*>(xr);
  float4 v1 = *reinterpret_cast<const float4*>(xr + 4);
  float4 v2 = *reinterpret_cast<const float4*>(xr + 8);
  float4 v3 = *reinterpret_cast<const float4*>(xr + 12);
  store_bf8(xb + (long)t * cH + lane * 16, v0, v1);
  store_bf8(xb + (long)t * cH + lane * 16 + 8, v2, v3);
  float xv[16];
  *reinterpret_cast<float4*>(&xv[0])  = v0;
  *reinterpret_cast<float4*>(&xv[4])  = v1;
  *reinterpret_cast<float4*>(&xv[8])  = v2;
  *reinterpret_cast<float4*>(&xv[12]) = v3;
  const float* g = gw + (long)lane * 16 * cE;
  float l[cE];
#pragma unroll
  for (int e = 0; e < cE; ++e) l[e] = 0.f;
#pragma unroll
  for (int i = 0; i < 16; ++i) {
    float4 ga = *reinterpret_cast<const float4*>(g + i * cE);
    float4 gb = *reinterpret_cast<const float4*>(g + i * cE + 4);
    float xi = xv[i];
    l[0] += xi * ga.x; l[1] += xi * ga.y; l[2] += xi * ga.z; l[3] += xi * ga.w;
    l[4] += xi * gb.x; l[5] += xi * gb.y; l[6] += xi * gb.z; l[7] += xi * gb.w;
  }
#pragma unroll
  for (int m = 1; m < 64; m <<= 1)
#pragma unroll
    for (int e = 0; e < cE; ++e)
      l[e] += __shfl_xor(l[e], m, 64);
  if (lane == 0) {
    int i0 = 0; float m0 = l[0];
#pragma unroll
    for (int e = 1; e < cE; ++e) if (l[e] > m0) { m0 = l[e]; i0 = e; }
    int i1 = -1; float m1 = -1e30f;
#pragma unroll
    for (int e = 0; e < cE; ++e) if (e != i0 && l[e] > m1) { m1 = l[e]; i1 = e; }
    float w0 = 1.f / (1.f + expf(m1 - m0));
    et[t * 2 + 0] = i0;  et[t * 2 + 1] = i1;
    wt[t * 2 + 0] = w0;  wt[t * 2 + 1] = 1.f - w0;
  }
}

// ---------------------------------------------------------------------------
// build compact per-expert token lists + inverse map (single block)
// ---------------------------------------------------------------------------
__global__ __launch_bounds__(256) void k_lists(
    const int* __restrict__ et, int* __restrict__ rowmap,
    int* __restrict__ cnt, int* __restrict__ off)
{
  __shared__ int c[cE], p[cE], o[cE];
  const int tid = threadIdx.x;
  if (tid < cE) { c[tid] = 0; p[tid] = 0; }
  __syncthreads();
  for (int i = tid; i < ROWS; i += 256) atomicAdd(&c[et[i]], 1);
  __syncthreads();
  if (tid == 0) {
    int s = 0;
    for (int e = 0; e < cE; ++e) { o[e] = s; s += c[e]; }
  }
  __syncthreads();
  for (int i = tid; i < ROWS; i += 256) {
    int e = et[i];
    int slot = atomicAdd(&p[e], 1);
    rowmap[i] = o[e] + slot;
  }
  if (tid < cE) { cnt[tid] = c[tid]; off[tid] = o[tid]; }
}

// ---------------------------------------------------------------------------
// transpose + fp32->bf16: in [P][Q] per batch -> out [Q][P] per batch
// ---------------------------------------------------------------------------
__global__ __launch_bounds__(256) void k_tconv(
    const float* __restrict__ in, unsigned short* __restrict__ out, int P, int Q)
{
  __shared__ float tile[32][33];
  const long es = (long)P * Q;
  const int e = blockIdx.z;
  in += e * es; out += e * es;
  const int c0 = blockIdx.x * 32, r0 = blockIdx.y * 32;
  const int tid = threadIdx.x;
  const int r = tid >> 3, c4 = (tid & 7) * 4;
  float4 v = *reinterpret_cast<const float4*>(in + (long)(r0 + r) * Q + c0 + c4);
  tile[r][c4 + 0] = v.x; tile[r][c4 + 1] = v.y;
  tile[r][c4 + 2] = v.z; tile[r][c4 + 3] = v.w;
  __syncthreads();
  const int cc = tid >> 3, rr4 = (tid & 7) * 4;
  ushort4 o;
  o.x = f2bf(tile[rr4 + 0][cc]);
  o.y = f2bf(tile[rr4 + 1][cc]);
  o.z = f2bf(tile[rr4 + 2][cc]);
  o.w = f2bf(tile[rr4 + 3][cc]);
  *reinterpret_cast<ushort4*>(out + (long)(c0 + cc) * P + r0 + rr4) = o;
}

// ---------------------------------------------------------------------------
// MFMA fold: D[m][n] = sum_k A[m][k] * B[n][k],  K = 256 fixed.
// tile 128x64, BK=32, register prefetch. grid = (N/64, M/128, E)
// ---------------------------------------------------------------------------
__global__ __launch_bounds__(256, 2) void k_foldm(
    const unsigned short* __restrict__ A, long sA,
    const float* __restrict__ B, long sB,
    unsigned short* __restrict__ D, long sD, int ldd)
{
  __shared__ __align__(16) unsigned short As[128 * LDA], Bs[64 * LDA];
  const int e = blockIdx.z;
  A += e * sA; B += e * sB; D += e * sD;
  const int m0 = blockIdx.y * 128, n0 = blockIdx.x * 64;
  const int tid = threadIdx.x;
  const int sr = tid >> 2, sk = (tid & 3) * 8;
  const unsigned short* a0 = A + (long)(m0 + sr) * 256 + sk;
  const unsigned short* a1 = a0 + (long)64 * 256;
  const float* br = B + (long)(n0 + sr) * 256 + sk;
  uint4 rA0, rA1; float4 rB0, rB1;
  auto load_slice = [&](int k0) {
    rA0 = *reinterpret_cast<const uint4*>(a0 + k0);
    rA1 = *reinterpret_cast<const uint4*>(a1 + k0);
    rB0 = *reinterpret_cast<const float4*>(br + k0);
    rB1 = *reinterpret_cast<const float4*>(br + k0 + 4);
  };
  load_slice(0);
  const int wid = tid >> 6, lane = tid & 63;
  const int wm = (wid >> 1) * 64, wn = (wid & 1) * 32;
  const int fr = lane & 15, fq = lane >> 4;
  float4v zf = {0.f, 0.f, 0.f, 0.f};
  float4v acc[4][2];
#pragma unroll
  for (int i = 0; i < 4; ++i) { acc[i][0] = zf; acc[i][1] = zf; }
  for (int k0 = 0; k0 < 256; k0 += 32) {
    *reinterpret_cast<uint4*>(&As[sr * LDA + sk]) = rA0;
    *reinterpret_cast<uint4*>(&As[(sr + 64) * LDA + sk]) = rA1;
    store_bf8(&Bs[sr * LDA + sk], rB0, rB1);
    if (k0 + 32 < 256) load_slice(k0 + 32);
    __syncthreads();
    short8 af[4], bf[2];
#pragma unroll
    for (int mi = 0; mi < 4; ++mi)
      af[mi] = *reinterpret_cast<const short8*>(&As[(wm + mi * 16 + fr) * LDA + fq * 8]);
#pragma unroll
    for (int nj = 0; nj < 2; ++nj)
      bf[nj] = *reinterpret_cast<const short8*>(&Bs[(wn + nj * 16 + fr) * LDA + fq * 8]);
#pragma unroll
    for (int mi = 0; mi < 4; ++mi)
#pragma unroll
      for (int nj = 0; nj < 2; ++nj)
        acc[mi][nj] = MFMA16(af[mi], bf[nj], acc[mi][nj], 0, 0, 0);
    __syncthreads();
  }
#pragma unroll
  for (int mi = 0; mi < 4; ++mi)
#pragma unroll
    for (int r = 0; r < 4; ++r) {
      int m = m0 + wm + mi * 16 + fq * 4 + r;
#pragma unroll
      for (int nj = 0; nj < 2; ++nj)
        D[(long)m * ldd + n0 + wn + nj * 16 + fr] = f2bf(acc[mi][nj][r]);
    }
}

// ---------------------------------------------------------------------------
// DENSE t1 GEMM + scatter epilogue — m97-style async staging.
// BK=64, unpadded LDS [128][64], global_load_lds width 16. grid = (32, 16)
// ---------------------------------------------------------------------------
__global__ __launch_bounds__(256, 2) void k_t1d(
    const unsigned short* __restrict__ xb, const unsigned short* __restrict__ b1t,
    unsigned short* __restrict__ t1, const int* __restrict__ et,
    const int* __restrict__ rowmap)
{
  __shared__ __align__(16) unsigned short As[128 * 64];
  __shared__ __align__(16) unsigned short Bs[128 * 64];
  const int tid = threadIdx.x;
  const int wid = tid >> 6, lane = tid & 63;
  const int m0 = blockIdx.y * 128;
  const int nb = blockIdx.x;                 // 0..31
  const int srow = wid * 32 + (lane >> 3);
  const int scol = (lane & 7) * 8;
  const unsigned short* gA = xb + (long)(m0 + srow) * cH + scol;
  const unsigned short* gB = b1t + (long)(nb * 128 + srow) * cH + scol;
  unsigned short* lA = As + wid * 32 * 64;   // wave-uniform
  unsigned short* lB = Bs + wid * 32 * 64;
  const int wm = (wid >> 1) * 64, wn = (wid & 1) * 64;
  const int fr = lane & 15, fq = lane >> 4;
  float4v zf = {0.f, 0.f, 0.f, 0.f};
  float4v acc[4][4];
#pragma unroll
  for (int i = 0; i < 4; ++i)
#pragma unroll
    for (int j = 0; j < 4; ++j) acc[i][j] = zf;
  for (int k0 = 0; k0 < cH; k0 += 64) {
#pragma unroll
    for (int j = 0; j < 4; ++j) {
      gld16(gA + k0 + (long)j * 8 * cH, lA + j * 8 * 64);
      gld16(gB + k0 + (long)j * 8 * cH, lB + j * 8 * 64);
    }
    __syncthreads();
#pragma unroll
    for (int ks = 0; ks < 2; ++ks) {
      short8 af[4], bf[4];
#pragma unroll
      for (int mi = 0; mi < 4; ++mi)
        af[mi] = *reinterpret_cast<const short8*>(
            &As[(wm + mi * 16 + fr) * 64 + ks * 32 + fq * 8]);
#pragma unroll
      for (int nj = 0; nj < 4; ++nj)
        bf[nj] = *reinterpret_cast<const short8*>(
            &Bs[(wn + nj * 16 + fr) * 64 + ks * 32 + fq * 8]);
#pragma unroll
      for (int mi = 0; mi < 4; ++mi)
#pragma unroll
        for (int nj = 0; nj < 4; ++nj)
          acc[mi][nj] = MFMA16(af[mi], bf[nj], acc[mi][nj], 0, 0, 0);
    }
    __syncthreads();
  }
  const int e_t = nb >> 2;
  const int colbase = (nb & 3) * 128 + wn;
#pragma unroll
  for (int mi = 0; mi < 4; ++mi)
#pragma unroll
    for (int r = 0; r < 4; ++r) {
      int t = m0 + wm + mi * 16 + fq * 4 + r;
      int crow = -1;
      if (et[2 * t] == e_t) crow = rowmap[2 * t];
      else if (et[2 * t + 1] == e_t) crow = rowmap[2 * t + 1];
      if (crow >= 0) {
#pragma unroll
        for (int nj = 0; nj < 4; ++nj)
          t1[(long)crow * 512 + colbase + nj * 16 + fr] = f2bf(acc[mi][nj][r]);
      }
    }
}

// ---------------------------------------------------------------------------
// dual GEMM: a = silu(t1g @ vgT^T) * (t1u @ vuT^T)  [rows x F], K=256
// async staging, unpadded LDS, BK=32, clamped staging rows. grid=(44,16,E)
// ---------------------------------------------------------------------------
__global__ __launch_bounds__(256, 2) void k_act(
    const unsigned short* __restrict__ t1,
    const unsigned short* __restrict__ vgT, const unsigned short* __restrict__ vuT,
    unsigned short* __restrict__ a, const int* __restrict__ cnt,
    const int* __restrict__ off)
{
  __shared__ __align__(16) unsigned short Ag[128 * 32], Au[128 * 32];
  __shared__ __align__(16) unsigned short Bg[64 * 32],  Bu[64 * 32];
  const int e = blockIdx.z, c = cnt[e], o = off[e];
  const int m0 = blockIdx.y * 128;
  if (m0 >= c) return;
  const int n0 = blockIdx.x * 64;
  const int tid = threadIdx.x;
  const int wid = tid >> 6, lane = tid & 63;
  const int sr16 = lane >> 2, sc = (lane & 3) * 8;
  const int ra0 = o + min(m0 + wid * 32 + sr16, c - 1);
  const int ra1 = o + min(m0 + wid * 32 + 16 + sr16, c - 1);
  const unsigned short* gAg0 = t1 + (long)ra0 * 512 + sc;
  const unsigned short* gAg1 = t1 + (long)ra1 * 512 + sc;
  const unsigned short* gBg = vgT + (long)e * cF * 256 + (long)(n0 + wid * 16 + sr16) * 256 + sc;
  const unsigned short* gBu = vuT + (long)e * cF * 256 + (long)(n0 + wid * 16 + sr16) * 256 + sc;
  unsigned short* lAg = Ag + wid * 32 * 32;
  unsigned short* lAu = Au + wid * 32 * 32;
  unsigned short* lBg = Bg + wid * 16 * 32;
  unsigned short* lBu = Bu + wid * 16 * 32;
  const int wm = (wid >> 1) * 64, wn = (wid & 1) * 32;
  const int fr = lane & 15, fq = lane >> 4;
  float4v zf = {0.f, 0.f, 0.f, 0.f};
  float4v accg[4][2], accu[4][2];
#pragma unroll
  for (int i = 0; i < 4; ++i) { accg[i][0] = zf; accg[i][1] = zf; accu[i][0] = zf; accu[i][1] = zf; }
  for (int k0 = 0; k0 < 256; k0 += 32) {
    gld16(gAg0 + k0, lAg);
    gld16(gAg1 + k0, lAg + 16 * 32);
    gld16(gAg0 + 256 + k0, lAu);
    gld16(gAg1 + 256 + k0, lAu + 16 * 32);
    gld16(gBg + k0, lBg);
    gld16(gBu + k0, lBu);
    __syncthreads();
    short8 ag[4], au[4], bg[2], bu[2];
#pragma unroll
    for (int mi = 0; mi < 4; ++mi) {
      ag[mi] = *reinterpret_cast<const short8*>(&Ag[(wm + mi * 16 + fr) * 32 + fq * 8]);
      au[mi] = *reinterpret_cast<const short8*>(&Au[(wm + mi * 16 + fr) * 32 + fq * 8]);
    }
#pragma unroll
    for (int nj = 0; nj < 2; ++nj) {
      bg[nj] = *reinterpret_cast<const short8*>(&Bg[(wn + nj * 16 + fr) * 32 + fq * 8]);
      bu[nj] = *reinterpret_cast<const short8*>(&Bu[(wn + nj * 16 + fr) * 32 + fq * 8]);
    }
#pragma unroll
    for (int mi = 0; mi < 4; ++mi)
#pragma unroll
      for (int nj = 0; nj < 2; ++nj) {
        accg[mi][nj] = MFMA16(ag[mi], bg[nj], accg[mi][nj], 0, 0, 0);
        accu[mi][nj] = MFMA16(au[mi], bu[nj], accu[mi][nj], 0, 0, 0);
      }
    __syncthreads();
  }
#pragma unroll
  for (int mi = 0; mi < 4; ++mi)
#pragma unroll
    for (int r = 0; r < 4; ++r) {
      int row = m0 + wm + mi * 16 + fq * 4 + r;
      if (row < c) {
#pragma unroll
        for (int nj = 0; nj < 2; ++nj) {
          float g = accg[mi][nj][r];
          float u = accu[mi][nj][r];
          float s = g / (1.f + expf(-g)) * u;
          a[(long)(o + row) * cF + n0 + wn + nj * 16 + fr] = f2bf(s);
        }
      }
    }
}

// ---------------------------------------------------------------------------
// t3p[ks] = a @ udT^T (split-K=4, plain fp32 stores).  [4][ROWS][256].
// async staging, unpadded LDS [64][64], BK=64, clamped rows, 11 iters.
// grid = (16, 32, E): x = n(0..3) | ksp(0..3)<<2
// ---------------------------------------------------------------------------
__global__ __launch_bounds__(256) void k_t3(
    const unsigned short* __restrict__ a, const unsigned short* __restrict__ udT,
    float* __restrict__ t3p, const int* __restrict__ cnt,
    const int* __restrict__ off)
{
  __shared__ __align__(16) unsigned short As[64 * 64], Bs[64 * 64];
  const int e = blockIdx.z, c = cnt[e], o = off[e];
  const int m0 = blockIdx.y * 64;
  if (m0 >= c) return;
  const int n0 = (blockIdx.x & 3) * 64;
  const int ksp = blockIdx.x >> 2;                 // 0..3
  const int kbase = ksp * 704;
  const int tid = threadIdx.x;
  const int wid = tid >> 6, lane = tid & 63;
  // staging: 128B rows, 8 rows/gld16; lane -> row base+(lane>>3), col (lane&7)*8
  const int sr8 = lane >> 3, sc = (lane & 7) * 8;
  const int ra0 = o + min(m0 + wid * 16 + sr8, c - 1);
  const int ra1 = o + min(m0 + wid * 16 + 8 + sr8, c - 1);
  const unsigned short* gA0 = a + (long)ra0 * cF + kbase + sc;
  const unsigned short* gA1 = a + (long)ra1 * cF + kbase + sc;
  const unsigned short* gB  = udT + (long)e * 256 * cF + (long)(n0 + wid * 16 + sr8) * cF + kbase + sc;
  unsigned short* lA = As + wid * 16 * 64;
  unsigned short* lB = Bs + wid * 16 * 64;
  const int wm = (wid >> 1) * 32, wn = (wid & 1) * 32;
  const int fr = lane & 15, fq = lane >> 4;
  float4v zf = {0.f, 0.f, 0.f, 0.f};
  float4v acc[2][2] = {{zf, zf}, {zf, zf}};
  for (int k0 = 0; k0 < 704; k0 += 64) {
    gld16(gA0 + k0, lA);
    gld16(gA1 + k0, lA + 8 * 64);
    gld16(gB + k0, lB);
    gld16(gB + (long)8 * cF + k0, lB + 8 * 64);
    __syncthreads();
#pragma unroll
    for (int ks = 0; ks < 2; ++ks) {
      short8 af[2], bf[2];
#pragma unroll
      for (int mi = 0; mi < 2; ++mi)
        af[mi] = *reinterpret_cast<const short8*>(
            &As[(wm + mi * 16 + fr) * 64 + ks * 32 + fq * 8]);
#pragma unroll
      for (int nj = 0; nj < 2; ++nj)
        bf[nj] = *reinterpret_cast<const short8*>(
            &Bs[(wn + nj * 16 + fr) * 64 + ks * 32 + fq * 8]);
#pragma unroll
      for (int mi = 0; mi < 2; ++mi)
#pragma unroll
        for (int nj = 0; nj < 2; ++nj)
          acc[mi][nj] = MFMA16(af[mi], bf[nj], acc[mi][nj], 0, 0, 0);
    }
    __syncthreads();
  }
  float* dstbase = t3p + (long)ksp * ROWS * 256;
#pragma unroll
  for (int mi = 0; mi < 2; ++mi)
#pragma unroll
    for (int r = 0; r < 4; ++r) {
      int row = m0 + wm + mi * 16 + fq * 4 + r;
      if (row < c) {
        float* dst = dstbase + (long)(o + row) * 256 + n0 + wn;
#pragma unroll
        for (int nj = 0; nj < 2; ++nj)
          dst[nj * 16 + fr] = acc[mi][nj][r];
      }
    }
}

// ---------------------------------------------------------------------------
// t3b bf16 = sum of 4 fp32 t3p partials (pure streaming). grid = 512.
// ---------------------------------------------------------------------------
__global__ __launch_bounds__(256) void k_red(
    const float* __restrict__ t3p, unsigned short* __restrict__ t3b)
{
  const long psz = (long)ROWS * 256;
  long i = ((long)blockIdx.x * 256 + threadIdx.x) * 8;
  float4 s0 = *reinterpret_cast<const float4*>(t3p + i);
  float4 s1 = *reinterpret_cast<const float4*>(t3p + i + 4);
#pragma unroll
  for (int q = 1; q < 4; ++q) {
    float4 a0 = *reinterpret_cast<const float4*>(t3p + q * psz + i);
    float4 a1 = *reinterpret_cast<const float4*>(t3p + q * psz + i + 4);
    s0.x += a0.x; s0.y += a0.y; s0.z += a0.z; s0.w += a0.w;
    s1.x += a1.x; s1.y += a1.y; s1.z += a1.z; s1.w += a1.w;
  }
  store_bf8(t3b + i, s0, s1);
}

// ---------------------------------------------------------------------------
// y = t3b @ vd2t^T   [rows x 1024] bf16, plain stores. K = 256.
// async staging (k_act pattern), unpadded LDS, BK=32. grid = (16, 16, E)
// ---------------------------------------------------------------------------
__global__ __launch_bounds__(256, 2) void k_y(
    const unsigned short* __restrict__ t3b, const unsigned short* __restrict__ vd2t,
    unsigned short* __restrict__ y, const int* __restrict__ cnt,
    const int* __restrict__ off)
{
  __shared__ __align__(16) unsigned short As[128 * 32], Bs[64 * 32];
  const int e = blockIdx.z, c = cnt[e], o = off[e];
  const int m0 = blockIdx.y * 128;
  if (m0 >= c) return;
  const int n0 = blockIdx.x * 64;
  const int tid = threadIdx.x;
  const int wid = tid >> 6, lane = tid & 63;
  const int sr16 = lane >> 2, sc = (lane & 3) * 8;
  const int ra0 = o + min(m0 + wid * 32 + sr16, c - 1);
  const int ra1 = o + min(m0 + wid * 32 + 16 + sr16, c - 1);
  const unsigned short* gA0 = t3b + (long)ra0 * 256 + sc;
  const unsigned short* gA1 = t3b + (long)ra1 * 256 + sc;
  const unsigned short* gB  = vd2t + (long)e * cH * 256 + (long)(n0 + wid * 16 + sr16) * 256 + sc;
  unsigned short* lA = As + wid * 32 * 32;
  unsigned short* lB = Bs + wid * 16 * 32;
  const int wm = (wid >> 1) * 64, wn = (wid & 1) * 32;
  const int fr = lane & 15, fq = lane >> 4;
  float4v zf = {0.f, 0.f, 0.f, 0.f};
  float4v acc[4][2];
#pragma unroll
  for (int i = 0; i < 4; ++i) { acc[i][0] = zf; acc[i][1] = zf; }
  for (int k0 = 0; k0 < 256; k0 += 32) {
    gld16(gA0 + k0, lA);
    gld16(gA1 + k0, lA + 16 * 32);
    gld16(gB + k0, lB);
    __syncthreads();
    short8 af[4], bf[2];
#pragma unroll
    for (int mi = 0; mi < 4; ++mi)
      af[mi] = *reinterpret_cast<const short8*>(&As[(wm + mi * 16 + fr) * 32 + fq * 8]);
#pragma unroll
    for (int nj = 0; nj < 2; ++nj)
      bf[nj] = *reinterpret_cast<const short8*>(&Bs[(wn + nj * 16 + fr) * 32 + fq * 8]);
#pragma unroll
    for (int mi = 0; mi < 4; ++mi)
#pragma unroll
      for (int nj = 0; nj < 2; ++nj)
        acc[mi][nj] = MFMA16(af[mi], bf[nj], acc[mi][nj], 0, 0, 0);
    __syncthreads();
  }
#pragma unroll
  for (int mi = 0; mi < 4; ++mi)
#pragma unroll
    for (int r = 0; r < 4; ++r) {
      int row = m0 + wm + mi * 16 + fq * 4 + r;
      if (row < c) {
#pragma unroll
        for (int nj = 0; nj < 2; ++nj)
          y[(long)(o + row) * cH + n0 + wn + nj * 16 + fr] = f2bf(acc[mi][nj][r]);
      }
    }
}

// ---------------------------------------------------------------------------
// out[t] = w0 * y[rowmap[2t]] + w1 * y[rowmap[2t+1]]   (pure write, no zero)
// ---------------------------------------------------------------------------
__global__ __launch_bounds__(256) void k_combine(
    const unsigned short* __restrict__ y, const float* __restrict__ wt,
    const int* __restrict__ rowmap, float* __restrict__ out)
{
  const int tid = threadIdx.x;
  const int t = blockIdx.x * 2 + (tid >> 7);
  const int h = (tid & 127) * 8;
  const int r0 = rowmap[2 * t], r1 = rowmap[2 * t + 1];
  const float w0 = wt[2 * t], w1 = wt[2 * t + 1];
  union { uint4 v; unsigned short s[8]; } ua, ub;
  ua.v = *reinterpret_cast<const uint4*>(y + (long)r0 * cH + h);
  ub.v = *reinterpret_cast<const uint4*>(y + (long)r1 * cH + h);
  float o[8];
#pragma unroll
  for (int i = 0; i < 8; ++i)
    o[i] = w0 * bf2f(ua.s[i]) + w1 * bf2f(ub.s[i]);
  float* dst = out + (long)t * cH + h;
  *reinterpret_cast<float4*>(dst)     = make_float4(o[0], o[1], o[2], o[3]);
  *reinterpret_cast<float4*>(dst + 4) = make_float4(o[4], o[5], o[6], o[7]);
}

// ---------------------------------------------------------------------------
extern "C" void kernel_launch(void* const* d_in, const int* in_sizes, int n_in,
                              void* d_out, int out_size, void* d_ws, size_t ws_size,
                              hipStream_t stream)
{
  const float* x  = (const float*)d_in[0];
  const float* gw = (const float*)d_in[1];
  const float* Ug = (const float*)d_in[2];
  const float* Cg = (const float*)d_in[3];
  const float* Vg = (const float*)d_in[4];
  const float* Uu = (const float*)d_in[5];
  const float* Cu = (const float*)d_in[6];
  const float* Vu = (const float*)d_in[7];
  const float* Ud = (const float*)d_in[8];
  const float* Cd = (const float*)d_in[9];
  const float* Vd = (const float*)d_in[10];
  float* out = (float*)d_out;

  // workspace layout (~79 MiB peak, with aliasing)
  char* w = (char*)d_ws;
  // region 0: [vgT 11.53 | b1t 8.39] phase-1; phase-2: t3p (16 MiB fp32 x4
  // partials) + t3b (2 MiB bf16 reduced) both alias it (18.87 <= 19.92 MB)
  unsigned short* vgT = (unsigned short*)w;
  float*          t3p = (float*)w;
  unsigned short* t3b = (unsigned short*)(w + (long)4 * ROWS * 256 * 4);
  w += (long)cE * cF * 256 * 2;                                               // 11.53
  unsigned short* b1t = (unsigned short*)w;  w += (long)cE * 512 * 1024 * 2;  // 8.39
  unsigned short* vd2t = (unsigned short*)w; w += (long)cE * cH * 256 * 2;    // 4.19
  // vuT phase-1; yb (8.39) aliases it in phase 2
  unsigned short* vuT = (unsigned short*)w;
  unsigned short* yb  = (unsigned short*)w;  w += (long)cE * cF * 256 * 2;    // 11.53
  unsigned short* udT = (unsigned short*)w;  w += (long)cE * 256 * cF * 2;    // 11.53
  // VdT consumed by fold 3; xb (bf16 x, 4.19 MB) aliases it afterwards
  unsigned short* VdT = (unsigned short*)w;
  unsigned short* xb  = (unsigned short*)w;  w += (long)cE * cH * 256 * 2;    // 4.19
  unsigned short* CgT = (unsigned short*)w;  w += (long)cR * cR * 2;          // 0.13
  unsigned short* CuT = (unsigned short*)w;  w += (long)cR * cR * 2;          // 0.13
  unsigned short* t1  = (unsigned short*)w;  w += (long)ROWS * 512 * 2;       // 4.19
  unsigned short* ab  = (unsigned short*)w;  w += (long)ROWS * cF * 2;        // 23.07
  float* wt   = (float*)w; w += ROWS * 4;
  int* et     = (int*)w; w += ROWS * 4;
  int* rowmap = (int*)w; w += ROWS * 4;
  int* cnt = (int*)w; w += cE * 4;
  int* off = (int*)w; w += cE * 4;

  // 1. transposes (fp32 -> bf16)
  k_tconv<<<dim3(cR / 32, cR / 32, 1), dim3(256), 0, stream>>>(Cg, CgT, cR, cR);
  k_tconv<<<dim3(cR / 32, cR / 32, 1), dim3(256), 0, stream>>>(Cu, CuT, cR, cR);
  k_tconv<<<dim3(cH / 32, cR / 32, cE), dim3(256), 0, stream>>>(Vd, VdT, cR, cH);
  k_tconv<<<dim3(cF / 32, cR / 32, cE), dim3(256), 0, stream>>>(Vg, vgT, cR, cF);
  k_tconv<<<dim3(cF / 32, cR / 32, cE), dim3(256), 0, stream>>>(Vu, vuT, cR, cF);
  k_tconv<<<dim3(cR / 32, cF / 32, cE), dim3(256), 0, stream>>>(Ud, udT, cF, cR);
  // 2. MFMA folds (all K=256)
  k_foldm<<<dim3(cH / 64, cR / 128, cE), dim3(256), 0, stream>>>(
      CgT, 0, Ug, (long)cH * cR, b1t, (long)512 * 1024, cH);
  k_foldm<<<dim3(cH / 64, cR / 128, cE), dim3(256), 0, stream>>>(
      CuT, 0, Uu, (long)cH * cR, b1t + (long)256 * 1024, (long)512 * 1024, cH);
  k_foldm<<<dim3(cR / 64, cH / 128, cE), dim3(256), 0, stream>>>(
      VdT, (long)cH * cR, Cd, 0, vd2t, (long)cH * 256, cR);
  // 3. gating + x->bf16 (xb overwrites dead VdT) + lists
  k_gating<<<dim3(cT / 4), dim3(256), 0, stream>>>(x, gw, xb, et, wt);
  k_lists<<<dim3(1), dim3(256), 0, stream>>>(et, rowmap, cnt, off);
  // 4. dense t1 GEMM (async staging) + scatter into compact rows
  k_t1d<<<dim3(32, cT / 128), dim3(256), 0, stream>>>(xb, b1t, t1, et, rowmap);
  // 5. a = silu(t1g @ Vg) * (t1u @ Vu)  (async staging)
  k_act<<<dim3(cF / 64, cT / 128, cE), dim3(256), 0, stream>>>(t1, vgT, vuT, ab, cnt, off);
  // 6. t3p = a @ Ud (split-K=4, async staging; aliases dead vgT+b1t)
  k_t3<<<dim3(16, cT / 64, cE), dim3(256), 0, stream>>>(ab, udT, t3p, cnt, off);
  // 7. t3b = bf16(sum of 4 partials)
  k_red<<<dim3(ROWS * 256 / (256 * 8)), dim3(256), 0, stream>>>(t3p, t3b);
  // 8. y = t3b @ Vd2 (async staging, plain bf16 stores; aliases dead vuT)
  k_y<<<dim3(cH / 64, cT / 128, cE), dim3(256), 0, stream>>>(t3b, vd2t, yb, cnt, off);
  // 9. out = w0*y[r0] + w1*y[r1]
  k_combine<<<dim3(cT / 2), dim3(256), 0, stream>>>(yb, wt, rowmap, out);
}